// Round 1
// baseline (608.420 us; speedup 1.0000x reference)
//
#include <hip/hip_runtime.h>
#include <hip/hip_bf16.h>
#include <stdint.h>

// Problem constants
#define BB 2
#define SS 2048
#define HIDD 2048
#define NHH 16
#define HDD 128
#define NROWS (BB*SS)        // 4096
#define QKVN (3*HIDD)        // 6144
#define SCALE_Q 0.08838834764831845f  // 1/sqrt(128)

typedef float f32x4 __attribute__((ext_vector_type(4)));
typedef short s16x8 __attribute__((ext_vector_type(8)));
typedef uint32_t u32;
typedef __attribute__((address_space(1))) const u32 gau32;
typedef __attribute__((address_space(3))) u32 lau32;

__device__ __forceinline__ ushort f2bf(float f) {
    u32 u = __builtin_bit_cast(u32, f);
    u32 r = (u + 0x7fffu + ((u >> 16) & 1u)) >> 16;
    return (ushort)r;
}
__device__ __forceinline__ float bf2f(ushort h) {
    u32 u = ((u32)h) << 16;
    return __builtin_bit_cast(float, u);
}

// ---------------- fp32 -> bf16 convert (vectorized, grid-stride) ----------
__global__ __launch_bounds__(256) void cvt_f32_bf16(const float* __restrict__ in,
                                                    ushort* __restrict__ out, int n4) {
    int i = blockIdx.x * 256 + threadIdx.x;
    int stride = gridDim.x * 256;
    for (; i < n4; i += stride) {
        float4 v = ((const float4*)in)[i];
        ushort4 o;
        o.x = f2bf(v.x); o.y = f2bf(v.y); o.z = f2bf(v.z); o.w = f2bf(v.w);
        ((ushort4*)out)[i] = o;
    }
}

// ---------------- RoPE cos/sin table: [2048][64] float2 ------------------
__global__ __launch_bounds__(256) void rope_table_k(float2* __restrict__ tab) {
    int idx = blockIdx.x * 256 + threadIdx.x;   // 131072 total
    if (idx >= SS * 64) return;
    int j = idx & 63;
    int s = idx >> 6;
    // inv_freq = 10000^(-(2j)/128) = exp2(-(j/64)*log2(10000))
    float e = -(float)j * (13.287712379549449f / 64.0f);
    float inv = exp2f(e);
    float ang = (float)s * inv;
    float sv, cv;
    sincosf(ang, &sv, &cv);
    tab[idx] = make_float2(cv, sv);
}

// ---------------- RoPE apply in-place on bf16 QKV; emit fp32 K out -------
__global__ __launch_bounds__(256) void rope_apply_k(ushort* __restrict__ qkv,
                                                    const float2* __restrict__ tab,
                                                    float* __restrict__ kout) {
    int p = blockIdx.x * 256 + threadIdx.x;     // 8388608 total pairs
    if (p >= NROWS * 2 * NHH * 64) return;
    int j  = p & 63;
    int h  = (p >> 6) & 15;
    int w  = (p >> 10) & 1;   // 0=q, 1=k
    int bs = p >> 11;
    int s  = bs & (SS - 1);
    size_t off = (size_t)bs * QKVN + (size_t)w * HIDD + h * HDD + 2 * j;
    u32 pr = *(const u32*)(qkv + off);
    float x1 = bf2f((ushort)(pr & 0xffffu));
    float x2 = bf2f((ushort)(pr >> 16));
    float2 cs = tab[s * 64 + j];
    float r1 = x1 * cs.x - x2 * cs.y;
    float r2 = x1 * cs.y + x2 * cs.x;
    if (w == 0) {            // fold score scale into Q
        r1 *= SCALE_Q; r2 *= SCALE_Q;
    } else {                 // K: also write fp32 output (unscaled)
        float* ko = kout + ((size_t)bs * NHH + h) * HDD + 2 * j;
        ko[0] = r1; ko[1] = r2;
    }
    u32 op = (u32)f2bf(r1) | ((u32)f2bf(r2) << 16);
    *(u32*)(qkv + off) = op;
}

// ---------------- bf16 GEMM, C = A * B^T  (A:[M,K], B:[N,K]) -------------
// 128x128 tile, BK=32, 4 waves 2x2, each wave 64x64 (4x4 frags 16x16x32)
template<int OUTF32>
__global__ __launch_bounds__(256) void gemm_bt(const ushort* __restrict__ A,
                                               const ushort* __restrict__ Bm,
                                               void* __restrict__ Cv,
                                               int M, int N, int K) {
    __shared__ ushort Alds[128 * 32];
    __shared__ ushort Blds[128 * 32];
    const int bn = blockIdx.x, bm = blockIdx.y;
    const int tid = threadIdx.x;
    const int w = tid >> 6, lane = tid & 63;
    const int wr = w >> 1, wc = w & 1;
    const int l16 = lane & 15, lq = lane >> 4;
    const int bm0 = bm * 128, bn0 = bn * 128;

    f32x4 acc[4][4] = {};

    for (int k0 = 0; k0 < K; k0 += 32) {
        __syncthreads();
        // stage A,B tiles (128x32 bf16 each) via global_load_lds width=16
        #pragma unroll
        for (int q = 0; q < 2; ++q) {
            int qq = w + q * 4;                // KB-chunk 0..7
            const ushort* ga = A + (size_t)(bm0 + qq * 16 + (lane >> 2)) * K + k0 + (lane & 3) * 8;
            __builtin_amdgcn_global_load_lds((gau32*)ga, (lau32*)(Alds + qq * 512), 16, 0, 0);
            const ushort* gb = Bm + (size_t)(bn0 + qq * 16 + (lane >> 2)) * K + k0 + (lane & 3) * 8;
            __builtin_amdgcn_global_load_lds((gau32*)gb, (lau32*)(Blds + qq * 512), 16, 0, 0);
        }
        __syncthreads();
        s16x8 af[4], bf[4];
        #pragma unroll
        for (int m = 0; m < 4; ++m)
            af[m] = *(const s16x8*)(Alds + (wr * 64 + m * 16 + l16) * 32 + lq * 8);
        #pragma unroll
        for (int n = 0; n < 4; ++n)
            bf[n] = *(const s16x8*)(Blds + (wc * 64 + n * 16 + l16) * 32 + lq * 8);
        #pragma unroll
        for (int m = 0; m < 4; ++m)
            #pragma unroll
            for (int n = 0; n < 4; ++n)
                acc[m][n] = __builtin_amdgcn_mfma_f32_16x16x32_bf16(af[m], bf[n], acc[m][n], 0, 0, 0);
    }

    #pragma unroll
    for (int m = 0; m < 4; ++m)
        #pragma unroll
        for (int n = 0; n < 4; ++n) {
            int row = bm0 + wr * 64 + m * 16 + lq * 4;
            int col = bn0 + wc * 64 + n * 16 + l16;
            if (OUTF32) {
                float* C = (float*)Cv;
                #pragma unroll
                for (int r = 0; r < 4; ++r)
                    C[(size_t)(row + r) * N + col] = acc[m][n][r];
            } else {
                ushort* C = (ushort*)Cv;
                #pragma unroll
                for (int r = 0; r < 4; ++r)
                    C[(size_t)(row + r) * N + col] = f2bf(acc[m][n][r]);
            }
        }
}

// ---------------- Flash attention --------------------------------------
// grid: 32 qtiles * B * NH = 1024 blocks; 256 threads = 4 waves x 16 q-rows
__global__ __launch_bounds__(256) void attn_k(const ushort* __restrict__ qkv,
                                              ushort* __restrict__ aout) {
    __shared__ ushort Klds[64 * 128];   // swizzled [kv][d]
    __shared__ ushort Vt[128 * 64];     // swizzled [d][kv]
    __shared__ ushort Plds[4 * 16 * 64];

    const int bid = blockIdx.x;
    const int qt = bid & 31;
    const int bh = bid >> 5;
    const int b = bh >> 4, h = bh & 15;
    const int tid = threadIdx.x;
    const int w = tid >> 6, lane = tid & 63;
    const int l16 = lane & 15, lq = lane >> 4;

    // Q a-frags for this wave's 16-row band (Q is already RoPE'd and scaled)
    s16x8 qf[4];
    {
        int qrow = qt * 64 + w * 16 + l16;
        size_t qbase = ((size_t)(b * SS + qrow)) * QKVN + h * HDD;
        #pragma unroll
        for (int kk = 0; kk < 4; ++kk)
            qf[kk] = *(const s16x8*)(qkv + qbase + kk * 32 + lq * 8);
    }

    f32x4 accO[8] = {};
    float mrow[4] = {-3e38f, -3e38f, -3e38f, -3e38f};
    float lrow[4] = {0.f, 0.f, 0.f, 0.f};

    char* Kb = (char*)Klds;
    char* Vb = (char*)Vt;
    char* Pb = (char*)Plds + w * 2048;

    for (int kv0 = 0; kv0 < SS; kv0 += 64) {
        __syncthreads();
        // stage K tile [64][128] and transposed V tile [128][64]
        for (int c = tid; c < 1024; c += 256) {
            int kvr = c >> 4, c8 = c & 15;
            size_t gK = ((size_t)(b * SS + kv0 + kvr)) * QKVN + HIDD + h * HDD + c8 * 8;
            uint4 kx = *(const uint4*)(qkv + gK);
            int kaddr = (kvr * 256 + c8 * 16) ^ ((kvr & 7) << 4);
            *(uint4*)(Kb + kaddr) = kx;
            uint4 vx = *(const uint4*)(qkv + gK + HIDD);
            const ushort* vs = (const ushort*)&vx;
            #pragma unroll
            for (int jj = 0; jj < 8; ++jj) {
                int d = c8 * 8 + jj;
                int vaddr = (d * 128 + kvr * 2) ^ ((d & 7) << 4);
                *(ushort*)(Vb + vaddr) = vs[jj];
            }
        }
        __syncthreads();

        // scores: S = Q (16x128) . K^T (64x128)^T -> 16x64
        f32x4 sc[4];
        #pragma unroll
        for (int nb = 0; nb < 4; ++nb) {
            sc[nb] = f32x4{0.f, 0.f, 0.f, 0.f};
            #pragma unroll
            for (int kk = 0; kk < 4; ++kk) {
                int krow = nb * 16 + l16;
                int kaddr = (krow * 256 + kk * 64 + lq * 16) ^ ((krow & 7) << 4);
                s16x8 kf = *(const s16x8*)(Kb + kaddr);
                sc[nb] = __builtin_amdgcn_mfma_f32_16x16x32_bf16(qf[kk], kf, sc[nb], 0, 0, 0);
            }
        }

        // online softmax (rows = lq*4+r, cols across 16-lane group)
        float rm[4];
        #pragma unroll
        for (int r = 0; r < 4; ++r)
            rm[r] = fmaxf(fmaxf(sc[0][r], sc[1][r]), fmaxf(sc[2][r], sc[3][r]));
        #pragma unroll
        for (int mask = 1; mask < 16; mask <<= 1)
            #pragma unroll
            for (int r = 0; r < 4; ++r)
                rm[r] = fmaxf(rm[r], __shfl_xor(rm[r], mask, 64));
        float mnew[4], scl[4];
        #pragma unroll
        for (int r = 0; r < 4; ++r) {
            mnew[r] = fmaxf(mrow[r], rm[r]);
            scl[r] = __expf(mrow[r] - mnew[r]);
            mrow[r] = mnew[r];
        }
        float rs[4] = {0.f, 0.f, 0.f, 0.f};
        #pragma unroll
        for (int nb = 0; nb < 4; ++nb)
            #pragma unroll
            for (int r = 0; r < 4; ++r) {
                float pv = __expf(sc[nb][r] - mnew[r]);
                sc[nb][r] = pv;
                rs[r] += pv;
            }
        #pragma unroll
        for (int mask = 1; mask < 16; mask <<= 1)
            #pragma unroll
            for (int r = 0; r < 4; ++r)
                rs[r] += __shfl_xor(rs[r], mask, 64);
        #pragma unroll
        for (int r = 0; r < 4; ++r)
            lrow[r] = lrow[r] * scl[r] + rs[r];
        #pragma unroll
        for (int ob = 0; ob < 8; ++ob)
            #pragma unroll
            for (int r = 0; r < 4; ++r)
                accO[ob][r] *= scl[r];

        // P (D-layout) -> LDS bf16 (A-layout read later)
        #pragma unroll
        for (int nb = 0; nb < 4; ++nb)
            #pragma unroll
            for (int r = 0; r < 4; ++r) {
                int prow = lq * 4 + r;
                int pcol = nb * 16 + l16;
                int paddr = (prow * 128 + pcol * 2) ^ ((prow & 7) << 4);
                *(ushort*)(Pb + paddr) = f2bf(sc[nb][r]);
            }
        __syncthreads();

        // O += P (16x64) . V (64x128)   [Vt staged as (Vt)^T bt-form]
        #pragma unroll
        for (int kk2 = 0; kk2 < 2; ++kk2) {
            int paddr = (l16 * 128 + kk2 * 64 + lq * 16) ^ ((l16 & 7) << 4);
            s16x8 pf = *(const s16x8*)(Pb + paddr);
            #pragma unroll
            for (int ob = 0; ob < 8; ++ob) {
                int d = ob * 16 + l16;
                int vaddr = (d * 128 + kk2 * 64 + lq * 16) ^ ((d & 7) << 4);
                s16x8 vf = *(const s16x8*)(Vb + vaddr);
                accO[ob] = __builtin_amdgcn_mfma_f32_16x16x32_bf16(pf, vf, accO[ob], 0, 0, 0);
            }
        }
    }

    // epilogue: normalize and store bf16 attn-out [4096][2048]
    float invl[4];
    #pragma unroll
    for (int r = 0; r < 4; ++r) invl[r] = 1.0f / lrow[r];
    int orow0 = b * SS + qt * 64 + w * 16 + lq * 4;
    #pragma unroll
    for (int ob = 0; ob < 8; ++ob) {
        int col = h * HDD + ob * 16 + l16;
        #pragma unroll
        for (int r = 0; r < 4; ++r)
            aout[(size_t)(orow0 + r) * HIDD + col] = f2bf(accO[ob][r] * invl[r]);
    }
}

// ---------------- launch -------------------------------------------------
extern "C" void kernel_launch(void* const* d_in, const int* in_sizes, int n_in,
                              void* d_out, int out_size, void* d_ws, size_t ws_size,
                              hipStream_t stream) {
    const float* x     = (const float*)d_in[0];
    const float* w_qkv = (const float*)d_in[1];
    const float* w_out = (const float*)d_in[2];
    float* out = (float*)d_out;

    char* ws = (char*)d_ws;
    ushort* qkv_bf  = (ushort*)(ws);                 // 50,331,648 B
    ushort* xbf     = (ushort*)(ws + 50331648);      // 16,777,216 B (reused as attn_out)
    ushort* wqkv_bf = (ushort*)(ws + 67108864);      // 25,165,824 B (reused as wout_bf)
    float2* tab     = (float2*)(ws + 92274688);      //  1,048,576 B

    // 1) converts
    cvt_f32_bf16<<<2048, 256, 0, stream>>>(x, xbf, (NROWS * HIDD) / 4);
    cvt_f32_bf16<<<2048, 256, 0, stream>>>(w_qkv, wqkv_bf, (QKVN * HIDD) / 4);
    // 2) rope table
    rope_table_k<<<(SS * 64) / 256, 256, 0, stream>>>(tab);
    // 3) QKV projection: [4096,6144] = xbf [4096,2048] * wqkv^T
    gemm_bt<0><<<dim3(QKVN / 128, NROWS / 128), 256, 0, stream>>>(xbf, wqkv_bf, qkv_bf,
                                                                  NROWS, QKVN, HIDD);
    // 4) RoPE on q (scaled) and k (also writes fp32 k output)
    rope_apply_k<<<(NROWS * 2 * NHH * 64) / 256, 256, 0, stream>>>(qkv_bf, tab,
                                                                   out + (size_t)NROWS * HIDD);
    // 5) flash attention -> attn_out (reuses xbf region)
    attn_k<<<32 * BB * NHH, 256, 0, stream>>>(qkv_bf, xbf);
    // 6) w_out convert (reuses wqkv_bf region) + output projection (fp32 out)
    cvt_f32_bf16<<<2048, 256, 0, stream>>>(w_out, wqkv_bf, (HIDD * HIDD) / 4);
    gemm_bt<1><<<dim3(HIDD / 128, NROWS / 128), 256, 0, stream>>>(xbf, wqkv_bf, out,
                                                                  NROWS, HIDD, HIDD);
}

// Round 3
// 351.846 us; speedup vs baseline: 1.7292x; 1.7292x over previous
//
#include <hip/hip_runtime.h>
#include <hip/hip_bf16.h>
#include <stdint.h>

// Problem constants
#define BB 2
#define SS 2048
#define HIDD 2048
#define NHH 16
#define HDD 128
#define NROWS (BB*SS)        // 4096
#define QKVN (3*HIDD)        // 6144
#define SCALE_Q 0.08838834764831845f  // 1/sqrt(128)

typedef float f32x4 __attribute__((ext_vector_type(4)));
typedef short s16x8 __attribute__((ext_vector_type(8)));
typedef uint32_t u32;
typedef __attribute__((address_space(1))) const u32 gau32;
typedef __attribute__((address_space(3))) u32 lau32;

__device__ __forceinline__ ushort f2bf(float f) {
    u32 u = __builtin_bit_cast(u32, f);
    u32 r = (u + 0x7fffu + ((u >> 16) & 1u)) >> 16;
    return (ushort)r;
}
__device__ __forceinline__ float bf2f(ushort h) {
    u32 u = ((u32)h) << 16;
    return __builtin_bit_cast(float, u);
}

// ---------------- fp32 -> bf16 convert (vectorized, grid-stride) ----------
__global__ __launch_bounds__(256) void cvt_f32_bf16(const float* __restrict__ in,
                                                    ushort* __restrict__ out, int n4) {
    int i = blockIdx.x * 256 + threadIdx.x;
    int stride = gridDim.x * 256;
    for (; i < n4; i += stride) {
        float4 v = ((const float4*)in)[i];
        ushort4 o;
        o.x = f2bf(v.x); o.y = f2bf(v.y); o.z = f2bf(v.z); o.w = f2bf(v.w);
        ((ushort4*)out)[i] = o;
    }
}

// ---------------- RoPE cos/sin table: [2048][64] float2 ------------------
__global__ __launch_bounds__(256) void rope_table_k(float2* __restrict__ tab) {
    int idx = blockIdx.x * 256 + threadIdx.x;
    if (idx >= SS * 64) return;
    int j = idx & 63;
    int s = idx >> 6;
    float e = -(float)j * (13.287712379549449f / 64.0f);
    float inv = exp2f(e);
    float ang = (float)s * inv;
    float sv, cv;
    sincosf(ang, &sv, &cv);
    tab[idx] = make_float2(cv, sv);
}

// ---------------- RoPE apply in-place on bf16 QKV; emit fp32 K out -------
__global__ __launch_bounds__(256) void rope_apply_k(ushort* __restrict__ qkv,
                                                    const float2* __restrict__ tab,
                                                    float* __restrict__ kout) {
    int p = blockIdx.x * 256 + threadIdx.x;
    if (p >= NROWS * 2 * NHH * 64) return;
    int j  = p & 63;
    int h  = (p >> 6) & 15;
    int w  = (p >> 10) & 1;   // 0=q, 1=k
    int bs = p >> 11;
    int s  = bs & (SS - 1);
    size_t off = (size_t)bs * QKVN + (size_t)w * HIDD + h * HDD + 2 * j;
    u32 pr = *(const u32*)(qkv + off);
    float x1 = bf2f((ushort)(pr & 0xffffu));
    float x2 = bf2f((ushort)(pr >> 16));
    float2 cs = tab[s * 64 + j];
    float r1 = x1 * cs.x - x2 * cs.y;
    float r2 = x1 * cs.y + x2 * cs.x;
    if (w == 0) {
        r1 *= SCALE_Q; r2 *= SCALE_Q;
    } else {
        float* ko = kout + ((size_t)bs * NHH + h) * HDD + 2 * j;
        ko[0] = r1; ko[1] = r2;
    }
    u32 op = (u32)f2bf(r1) | ((u32)f2bf(r2) << 16);
    *(u32*)(qkv + off) = op;
}

// ---------------- V transpose: qkv V section -> VT[b][h][d][s] -----------
__global__ __launch_bounds__(256) void vtrans_k(const ushort* __restrict__ qkv,
                                                ushort* __restrict__ vt) {
    __shared__ ushort tile[64 * 66];   // pad 2 -> row stride 132B
    int bid = blockIdx.x;              // 2048 = 32 bh * 32 st * 2 dt
    int dt = bid & 1, st = (bid >> 1) & 31, bh = bid >> 6;
    int b = bh >> 4, h = bh & 15;
    int s0 = st * 64, d0 = dt * 64;
    int tid = threadIdx.x;
    #pragma unroll
    for (int i = 0; i < 2; ++i) {
        int idx = tid + i * 256;
        int row = idx >> 3, c8 = idx & 7;
        const ushort* src = qkv + (size_t)(b * SS + s0 + row) * QKVN + 2 * HIDD + h * HDD + d0 + c8 * 8;
        uint4 v = *(const uint4*)src;
        const u32* vw = (const u32*)&v;
        u32* dst = (u32*)((char*)tile + row * 132 + c8 * 16);
        dst[0] = vw[0]; dst[1] = vw[1]; dst[2] = vw[2]; dst[3] = vw[3];
    }
    __syncthreads();
    #pragma unroll
    for (int i = 0; i < 2; ++i) {
        int idx = tid + i * 256;
        int d = idx >> 3, sc8 = idx & 7;
        u32 wv[4];
        #pragma unroll
        for (int k = 0; k < 4; ++k) {
            ushort a = tile[(sc8 * 8 + 2 * k) * 66 + d];
            ushort c = tile[(sc8 * 8 + 2 * k + 1) * 66 + d];
            wv[k] = (u32)a | ((u32)c << 16);
        }
        ushort* dst = vt + ((size_t)(b * NHH + h) * HDD + d0 + d) * SS + s0 + sc8 * 8;
        *(uint4*)dst = *(const uint4*)wv;
    }
}

// ---------------- bf16 GEMM, C = A * B^T  (A:[M,K], B:[N,K]) -------------
template<int OUTF32>
__global__ __launch_bounds__(256) void gemm_bt(const ushort* __restrict__ A,
                                               const ushort* __restrict__ Bm,
                                               void* __restrict__ Cv,
                                               int M, int N, int K) {
    __shared__ ushort Alds[128 * 32];
    __shared__ ushort Blds[128 * 32];
    const int bn = blockIdx.x, bm = blockIdx.y;
    const int tid = threadIdx.x;
    const int w = tid >> 6, lane = tid & 63;
    const int wr = w >> 1, wc = w & 1;
    const int l16 = lane & 15, lq = lane >> 4;
    const int bm0 = bm * 128, bn0 = bn * 128;

    f32x4 acc[4][4] = {};

    for (int k0 = 0; k0 < K; k0 += 32) {
        __syncthreads();
        #pragma unroll
        for (int q = 0; q < 2; ++q) {
            int qq = w + q * 4;
            const ushort* ga = A + (size_t)(bm0 + qq * 16 + (lane >> 2)) * K + k0 + (lane & 3) * 8;
            __builtin_amdgcn_global_load_lds((gau32*)ga, (lau32*)(Alds + qq * 512), 16, 0, 0);
            const ushort* gb = Bm + (size_t)(bn0 + qq * 16 + (lane >> 2)) * K + k0 + (lane & 3) * 8;
            __builtin_amdgcn_global_load_lds((gau32*)gb, (lau32*)(Blds + qq * 512), 16, 0, 0);
        }
        __syncthreads();
        s16x8 af[4], bf[4];
        #pragma unroll
        for (int m = 0; m < 4; ++m)
            af[m] = *(const s16x8*)(Alds + (wr * 64 + m * 16 + l16) * 32 + lq * 8);
        #pragma unroll
        for (int n = 0; n < 4; ++n)
            bf[n] = *(const s16x8*)(Blds + (wc * 64 + n * 16 + l16) * 32 + lq * 8);
        #pragma unroll
        for (int m = 0; m < 4; ++m)
            #pragma unroll
            for (int n = 0; n < 4; ++n)
                acc[m][n] = __builtin_amdgcn_mfma_f32_16x16x32_bf16(af[m], bf[n], acc[m][n], 0, 0, 0);
    }

    #pragma unroll
    for (int m = 0; m < 4; ++m)
        #pragma unroll
        for (int n = 0; n < 4; ++n) {
            int row = bm0 + wr * 64 + m * 16 + lq * 4;
            int col = bn0 + wc * 64 + n * 16 + l16;
            if (OUTF32) {
                float* C = (float*)Cv;
                #pragma unroll
                for (int r = 0; r < 4; ++r)
                    C[(size_t)(row + r) * N + col] = acc[m][n][r];
            } else {
                ushort* C = (ushort*)Cv;
                #pragma unroll
                for (int r = 0; r < 4; ++r)
                    C[(size_t)(row + r) * N + col] = f2bf(acc[m][n][r]);
            }
        }
}

// ---------------- Flash attention (v2) ----------------------------------
// 512 blocks = 16 qtiles x 32 bh; 4 waves x 32 q-rows; KV tile 64.
// S^T = mfma(K,Q): lane-local softmax columns; P via swizzled per-wave LDS.
// K/VT staged by global_load_lds (linear dest, inverse-swizzled source).
// LDS map (dynamic, 80KB): K dbuf @0/@16384, V dbuf @32768/@49152, P @65536.
__global__ __launch_bounds__(256, 2) void attn_k(const ushort* __restrict__ qkv,
                                                 const ushort* __restrict__ vt,
                                                 ushort* __restrict__ aout) {
    extern __shared__ char smem[];

    const int bid = blockIdx.x;
    // bijective XCD swizzle: 512 blocks = 8 xcd * 64; same-bh tiles share xcd
    const int L = (bid & 7) * 64 + (bid >> 3);
    const int qt = L & 15, bh = L >> 4;
    const int b = bh >> 4, h = bh & 15;
    const int tid = threadIdx.x;
    const int w = tid >> 6, lane = tid & 63;
    const int l16 = lane & 15, lq = lane >> 4;

    // Q B-frags: q = qt*128 + w*32 + qb*16 + l16, d = kk*32 + lq*8 + j
    s16x8 qf[2][4];
    #pragma unroll
    for (int qb = 0; qb < 2; ++qb) {
        size_t qbase = (size_t)(b * SS + qt * 128 + w * 32 + qb * 16 + l16) * QKVN + h * HDD;
        #pragma unroll
        for (int kk = 0; kk < 4; ++kk)
            qf[qb][kk] = *(const s16x8*)(qkv + qbase + kk * 32 + lq * 8);
    }

    // staging source pointers (inverse-swizzled global addresses)
    const ushort* ksrc[4];
    const ushort* vsrc[4];
    #pragma unroll
    for (int i = 0; i < 4; ++i) {
        int krow = w * 16 + i * 4 + (lane >> 4);         // K tile row (kv)
        int kcolb = ((lane & 15) * 16) ^ ((krow & 7) << 4);
        ksrc[i] = qkv + (size_t)(b * SS + krow) * QKVN + HIDD + h * HDD + kcolb / 2;
        int drow = w * 32 + i * 8 + (lane >> 3);         // VT tile row (d)
        int vcolb = ((lane & 7) * 16) ^ ((drow & 7) << 4);
        vsrc[i] = vt + ((size_t)(b * NHH + h) * HDD + drow) * SS + vcolb / 2;
    }

    f32x4 accO[2][8] = {};
    float mrow[2] = {-3e38f, -3e38f};
    float lrow[2] = {0.f, 0.f};

    char* Pb = smem + 65536 + w * 4096;
    const int kswz = (l16 & 7) << 4;
    const int pswz = (l16 & 3) << 5;

    // prologue: stage tile 0
    {
        char* kb = smem + w * 4096;
        char* vb = smem + 32768 + w * 4096;
        #pragma unroll
        for (int i = 0; i < 4; ++i) {
            __builtin_amdgcn_global_load_lds((gau32*)ksrc[i], (lau32*)(kb + i * 1024), 16, 0, 0);
            ksrc[i] += 64 * QKVN;
            __builtin_amdgcn_global_load_lds((gau32*)vsrc[i], (lau32*)(vb + i * 1024), 16, 0, 0);
            vsrc[i] += 64;
        }
    }
    __syncthreads();

    for (int t = 0; t < 32; ++t) {
        const int cur = t & 1;
        if (t < 31) {
            char* kb = smem + (cur ^ 1) * 16384 + w * 4096;
            char* vb = smem + 32768 + (cur ^ 1) * 16384 + w * 4096;
            #pragma unroll
            for (int i = 0; i < 4; ++i) {
                __builtin_amdgcn_global_load_lds((gau32*)ksrc[i], (lau32*)(kb + i * 1024), 16, 0, 0);
                ksrc[i] += 64 * QKVN;
                __builtin_amdgcn_global_load_lds((gau32*)vsrc[i], (lau32*)(vb + i * 1024), 16, 0, 0);
                vsrc[i] += 64;
            }
        }
        const char* Kb = smem + cur * 16384;
        const char* Vb = smem + 32768 + cur * 16384;

        // S^T = K . Q : sc[qb][nb] holds S[q=qb*16+l16][kv=nb*16+lq*4+r]
        f32x4 sc[2][4] = {};
        #pragma unroll
        for (int nb = 0; nb < 4; ++nb) {
            int rbase = (nb * 16 + l16) * 256;
            #pragma unroll
            for (int kk = 0; kk < 4; ++kk) {
                s16x8 kf = *(const s16x8*)(Kb + rbase + ((kk * 64 + lq * 16) ^ kswz));
                sc[0][nb] = __builtin_amdgcn_mfma_f32_16x16x32_bf16(kf, qf[0][kk], sc[0][nb], 0, 0, 0);
                sc[1][nb] = __builtin_amdgcn_mfma_f32_16x16x32_bf16(kf, qf[1][kk], sc[1][nb], 0, 0, 0);
            }
        }

        // online softmax per qb (full row for q=qb*16+l16 spread over lq groups)
        float scl[2];
        #pragma unroll
        for (int qb = 0; qb < 2; ++qb) {
            float m0 = fmaxf(fmaxf(sc[qb][0][0], sc[qb][0][1]), fmaxf(sc[qb][0][2], sc[qb][0][3]));
            #pragma unroll
            for (int nb = 1; nb < 4; ++nb) {
                m0 = fmaxf(m0, fmaxf(fmaxf(sc[qb][nb][0], sc[qb][nb][1]),
                                     fmaxf(sc[qb][nb][2], sc[qb][nb][3])));
            }
            m0 = fmaxf(m0, __shfl_xor(m0, 16));
            m0 = fmaxf(m0, __shfl_xor(m0, 32));
            float mnew = fmaxf(mrow[qb], m0);
            scl[qb] = __expf(mrow[qb] - mnew);
            mrow[qb] = mnew;
            float s = 0.f;
            #pragma unroll
            for (int nb = 0; nb < 4; ++nb)
                #pragma unroll
                for (int r = 0; r < 4; ++r) {
                    float pv = __expf(sc[qb][nb][r] - mnew);
                    sc[qb][nb][r] = pv;
                    s += pv;
                }
            s += __shfl_xor(s, 16);
            s += __shfl_xor(s, 32);
            lrow[qb] = lrow[qb] * scl[qb] + s;
        }
        // rescale accO (q = qb*16 + lq*4 + r rows)
        #pragma unroll
        for (int r = 0; r < 4; ++r) {
            float s0 = __shfl(scl[0], lq * 4 + r);
            float s1 = __shfl(scl[1], lq * 4 + r);
            #pragma unroll
            for (int ob = 0; ob < 8; ++ob) {
                accO[0][ob][r] *= s0;
                accO[1][ob][r] *= s1;
            }
        }

        // P -> per-wave swizzled LDS ([32 q][64 kv] bf16, ^((q&3)<<5))
        #pragma unroll
        for (int qb = 0; qb < 2; ++qb) {
            int qrow = (qb * 16 + l16) * 128;
            #pragma unroll
            for (int nb = 0; nb < 4; ++nb) {
                u32 lo = (u32)f2bf(sc[qb][nb][0]) | ((u32)f2bf(sc[qb][nb][1]) << 16);
                u32 hi = (u32)f2bf(sc[qb][nb][2]) | ((u32)f2bf(sc[qb][nb][3]) << 16);
                uint2 v2 = make_uint2(lo, hi);
                *(uint2*)(Pb + qrow + ((nb * 32 + lq * 8) ^ pswz)) = v2;
            }
        }

        // O += P . V
        #pragma unroll
        for (int kk2 = 0; kk2 < 2; ++kk2) {
            int cb = (kk2 * 64 + lq * 16);
            s16x8 pf0 = *(const s16x8*)(Pb + l16 * 128 + (cb ^ pswz));
            s16x8 pf1 = *(const s16x8*)(Pb + (16 + l16) * 128 + (cb ^ pswz));
            #pragma unroll
            for (int ob = 0; ob < 8; ++ob) {
                int d = ob * 16 + l16;
                s16x8 vf = *(const s16x8*)(Vb + d * 128 + (cb ^ ((d & 7) << 4)));
                accO[0][ob] = __builtin_amdgcn_mfma_f32_16x16x32_bf16(pf0, vf, accO[0][ob], 0, 0, 0);
                accO[1][ob] = __builtin_amdgcn_mfma_f32_16x16x32_bf16(pf1, vf, accO[1][ob], 0, 0, 0);
            }
        }
        __syncthreads();
    }

    // epilogue
    float inv0 = 1.f / lrow[0], inv1 = 1.f / lrow[1];
    #pragma unroll
    for (int r = 0; r < 4; ++r) {
        float i0 = __shfl(inv0, lq * 4 + r);
        float i1 = __shfl(inv1, lq * 4 + r);
        int row0 = b * SS + qt * 128 + w * 32 + lq * 4 + r;
        #pragma unroll
        for (int ob = 0; ob < 8; ++ob) {
            int col = h * HDD + ob * 16 + l16;
            aout[(size_t)row0 * HIDD + col] = f2bf(accO[0][ob][r] * i0);
            aout[(size_t)(row0 + 16) * HIDD + col] = f2bf(accO[1][ob][r] * i1);
        }
    }
}

// ---------------- launch -------------------------------------------------
extern "C" void kernel_launch(void* const* d_in, const int* in_sizes, int n_in,
                              void* d_out, int out_size, void* d_ws, size_t ws_size,
                              hipStream_t stream) {
    const float* x     = (const float*)d_in[0];
    const float* w_qkv = (const float*)d_in[1];
    const float* w_out = (const float*)d_in[2];
    float* out = (float*)d_out;

    char* ws = (char*)d_ws;
    ushort* qkv_bf  = (ushort*)(ws);                        // 50,331,648 B
    ushort* xbf     = (ushort*)(ws + 50331648);             // 16,777,216 B (-> attn out)
    ushort* wq_bf   = (ushort*)(ws + 67108864);             // 25,165,824 B region
    ushort* vtbuf   = (ushort*)(ws + 67108864);             //   VT reuses it (16.8MB)
    ushort* wout_bf = (ushort*)(ws + 67108864 + 16777216);  //   + w_out bf16 (8.4MB)
    float2* tab     = (float2*)(ws + 92274688);             //  1,048,576 B

    cvt_f32_bf16<<<2048, 256, 0, stream>>>(x, xbf, (NROWS * HIDD) / 4);
    cvt_f32_bf16<<<2048, 256, 0, stream>>>(w_qkv, wq_bf, (QKVN * HIDD) / 4);
    rope_table_k<<<(SS * 64) / 256, 256, 0, stream>>>(tab);

    gemm_bt<0><<<dim3(QKVN / 128, NROWS / 128), 256, 0, stream>>>(xbf, wq_bf, qkv_bf,
                                                                  NROWS, QKVN, HIDD);
    rope_apply_k<<<(NROWS * 2 * NHH * 64) / 256, 256, 0, stream>>>(qkv_bf, tab,
                                                                   out + (size_t)NROWS * HIDD);
    // V transpose into the (now free) w_qkv region
    vtrans_k<<<2048, 256, 0, stream>>>(qkv_bf, vtbuf);
    cvt_f32_bf16<<<2048, 256, 0, stream>>>(w_out, wout_bf, (HIDD * HIDD) / 4);

    attn_k<<<512, 256, 81920, stream>>>(qkv_bf, vtbuf, xbf);

    gemm_bt<1><<<dim3(HIDD / 128, NROWS / 128), 256, 0, stream>>>(xbf, wout_bf, out,
                                                                  NROWS, HIDD, HIDD);
}

// Round 4
// 337.269 us; speedup vs baseline: 1.8040x; 1.0432x over previous
//
#include <hip/hip_runtime.h>
#include <hip/hip_bf16.h>
#include <stdint.h>

// Problem constants
#define BB 2
#define SS 2048
#define HIDD 2048
#define NHH 16
#define HDD 128
#define NROWS (BB*SS)        // 4096
#define QKVN (3*HIDD)        // 6144
#define SCALE_Q 0.08838834764831845f  // 1/sqrt(128)

typedef float f32x4 __attribute__((ext_vector_type(4)));
typedef short s16x8 __attribute__((ext_vector_type(8)));
typedef uint32_t u32;
typedef __attribute__((address_space(1))) const u32 gau32;
typedef __attribute__((address_space(3))) u32 lau32;

__device__ __forceinline__ ushort f2bf(float f) {
    u32 u = __builtin_bit_cast(u32, f);
    u32 r = (u + 0x7fffu + ((u >> 16) & 1u)) >> 16;
    return (ushort)r;
}
__device__ __forceinline__ float bf2f(ushort h) {
    u32 u = ((u32)h) << 16;
    return __builtin_bit_cast(float, u);
}

// ---------------- fp32 -> bf16 convert (vectorized, grid-stride) ----------
__global__ __launch_bounds__(256) void cvt_f32_bf16(const float* __restrict__ in,
                                                    ushort* __restrict__ out, int n4) {
    int i = blockIdx.x * 256 + threadIdx.x;
    int stride = gridDim.x * 256;
    for (; i < n4; i += stride) {
        float4 v = ((const float4*)in)[i];
        ushort4 o;
        o.x = f2bf(v.x); o.y = f2bf(v.y); o.z = f2bf(v.z); o.w = f2bf(v.w);
        ((ushort4*)out)[i] = o;
    }
}

// ---------------- RoPE cos/sin table: [2048][64] float2 ------------------
__global__ __launch_bounds__(256) void rope_table_k(float2* __restrict__ tab) {
    int idx = blockIdx.x * 256 + threadIdx.x;
    if (idx >= SS * 64) return;
    int j = idx & 63;
    int s = idx >> 6;
    float e = -(float)j * (13.287712379549449f / 64.0f);
    float inv = exp2f(e);
    float ang = (float)s * inv;
    float sv, cv;
    sincosf(ang, &sv, &cv);
    tab[idx] = make_float2(cv, sv);
}

// ---------------- RoPE apply in-place on bf16 QKV; emit fp32 K out -------
__global__ __launch_bounds__(256) void rope_apply_k(ushort* __restrict__ qkv,
                                                    const float2* __restrict__ tab,
                                                    float* __restrict__ kout) {
    int p = blockIdx.x * 256 + threadIdx.x;
    if (p >= NROWS * 2 * NHH * 64) return;
    int j  = p & 63;
    int h  = (p >> 6) & 15;
    int w  = (p >> 10) & 1;   // 0=q, 1=k
    int bs = p >> 11;
    int s  = bs & (SS - 1);
    size_t off = (size_t)bs * QKVN + (size_t)w * HIDD + h * HDD + 2 * j;
    u32 pr = *(const u32*)(qkv + off);
    float x1 = bf2f((ushort)(pr & 0xffffu));
    float x2 = bf2f((ushort)(pr >> 16));
    float2 cs = tab[s * 64 + j];
    float r1 = x1 * cs.x - x2 * cs.y;
    float r2 = x1 * cs.y + x2 * cs.x;
    if (w == 0) {
        r1 *= SCALE_Q; r2 *= SCALE_Q;
    } else {
        float* ko = kout + ((size_t)bs * NHH + h) * HDD + 2 * j;
        ko[0] = r1; ko[1] = r2;
    }
    u32 op = (u32)f2bf(r1) | ((u32)f2bf(r2) << 16);
    *(u32*)(qkv + off) = op;
}

// ---------------- V transpose: qkv V section -> VT[b][h][d][s] -----------
__global__ __launch_bounds__(256) void vtrans_k(const ushort* __restrict__ qkv,
                                                ushort* __restrict__ vt) {
    __shared__ ushort tile[64 * 66];
    int bid = blockIdx.x;              // 2048 = 32 bh * 32 st * 2 dt
    int dt = bid & 1, st = (bid >> 1) & 31, bh = bid >> 6;
    int b = bh >> 4, h = bh & 15;
    int s0 = st * 64, d0 = dt * 64;
    int tid = threadIdx.x;
    #pragma unroll
    for (int i = 0; i < 2; ++i) {
        int idx = tid + i * 256;
        int row = idx >> 3, c8 = idx & 7;
        const ushort* src = qkv + (size_t)(b * SS + s0 + row) * QKVN + 2 * HIDD + h * HDD + d0 + c8 * 8;
        uint4 v = *(const uint4*)src;
        const u32* vw = (const u32*)&v;
        u32* dst = (u32*)((char*)tile + row * 132 + c8 * 16);
        dst[0] = vw[0]; dst[1] = vw[1]; dst[2] = vw[2]; dst[3] = vw[3];
    }
    __syncthreads();
    #pragma unroll
    for (int i = 0; i < 2; ++i) {
        int idx = tid + i * 256;
        int d = idx >> 3, sc8 = idx & 7;
        u32 wv[4];
        #pragma unroll
        for (int k = 0; k < 4; ++k) {
            ushort a = tile[(sc8 * 8 + 2 * k) * 66 + d];
            ushort c = tile[(sc8 * 8 + 2 * k + 1) * 66 + d];
            wv[k] = (u32)a | ((u32)c << 16);
        }
        ushort* dst = vt + ((size_t)(b * NHH + h) * HDD + d0 + d) * SS + s0 + sc8 * 8;
        *(uint4*)dst = *(const uint4*)wv;
    }
}

// ---------------- old 128x128 2-phase GEMM (kept for output projection) --
template<int OUTF32>
__global__ __launch_bounds__(256) void gemm_bt(const ushort* __restrict__ A,
                                               const ushort* __restrict__ Bm,
                                               void* __restrict__ Cv,
                                               int M, int N, int K) {
    __shared__ ushort Alds[128 * 32];
    __shared__ ushort Blds[128 * 32];
    const int bn = blockIdx.x, bm = blockIdx.y;
    const int tid = threadIdx.x;
    const int w = tid >> 6, lane = tid & 63;
    const int wr = w >> 1, wc = w & 1;
    const int l16 = lane & 15, lq = lane >> 4;
    const int bm0 = bm * 128, bn0 = bn * 128;

    f32x4 acc[4][4] = {};

    for (int k0 = 0; k0 < K; k0 += 32) {
        __syncthreads();
        #pragma unroll
        for (int q = 0; q < 2; ++q) {
            int qq = w + q * 4;
            const ushort* ga = A + (size_t)(bm0 + qq * 16 + (lane >> 2)) * K + k0 + (lane & 3) * 8;
            __builtin_amdgcn_global_load_lds((gau32*)ga, (lau32*)(Alds + qq * 512), 16, 0, 0);
            const ushort* gb = Bm + (size_t)(bn0 + qq * 16 + (lane >> 2)) * K + k0 + (lane & 3) * 8;
            __builtin_amdgcn_global_load_lds((gau32*)gb, (lau32*)(Blds + qq * 512), 16, 0, 0);
        }
        __syncthreads();
        s16x8 af[4], bf[4];
        #pragma unroll
        for (int m = 0; m < 4; ++m)
            af[m] = *(const s16x8*)(Alds + (wr * 64 + m * 16 + l16) * 32 + lq * 8);
        #pragma unroll
        for (int n = 0; n < 4; ++n)
            bf[n] = *(const s16x8*)(Blds + (wc * 64 + n * 16 + l16) * 32 + lq * 8);
        #pragma unroll
        for (int m = 0; m < 4; ++m)
            #pragma unroll
            for (int n = 0; n < 4; ++n)
                acc[m][n] = __builtin_amdgcn_mfma_f32_16x16x32_bf16(af[m], bf[n], acc[m][n], 0, 0, 0);
    }

    #pragma unroll
    for (int m = 0; m < 4; ++m)
        #pragma unroll
        for (int n = 0; n < 4; ++n) {
            int row = bm0 + wr * 64 + m * 16 + lq * 4;
            int col = bn0 + wc * 64 + n * 16 + l16;
            if (OUTF32) {
                float* C = (float*)Cv;
                #pragma unroll
                for (int r = 0; r < 4; ++r)
                    C[(size_t)(row + r) * N + col] = acc[m][n][r];
            } else {
                ushort* C = (ushort*)Cv;
                #pragma unroll
                for (int r = 0; r < 4; ++r)
                    C[(size_t)(row + r) * N + col] = f2bf(acc[m][n][r]);
            }
        }
}

// ---------------- 256x256 8-phase GEMM, C = A * B^T, K=2048 --------------
// 512 thr = 8 waves (2M x 4N), per-wave C 128x64, BK=64, LDS 128KB 2-dbuf.
// T2 swizzle: cb ^= ((row&7)<<4) both-sides; T4 counted vmcnt(4) at P4/P8;
// T5 setprio around 16-MFMA clusters. Reads front-loaded (12+12+0+0).
#define GL_LDS(s, d) __builtin_amdgcn_global_load_lds((gau32*)(s), (lau32*)(d), 16, 0, 0)
#define BAR() __builtin_amdgcn_s_barrier()
#define VMW4() { asm volatile("s_waitcnt vmcnt(4)" ::: "memory"); __builtin_amdgcn_sched_barrier(0); }
#define LGKM0() { asm volatile("s_waitcnt lgkmcnt(0)" ::: "memory"); __builtin_amdgcn_sched_barrier(0); }

#define ST_A(bb, h, kc) { \
    const ushort* _s = Ab + (size_t)((h) * 128 * 2048 + (kc)) + off0; \
    GL_LDS(_s, smem + (bb) * 32768 + (h) * 16384 + w * 1024); \
    GL_LDS(_s + 64 * 2048, smem + (bb) * 32768 + (h) * 16384 + (8 + w) * 1024); }
#define ST_B(bb, h, kc) { \
    const ushort* _s = Bb + (size_t)((h) * 128 * 2048 + (kc)) + off0; \
    GL_LDS(_s, smem + 65536 + (bb) * 32768 + (h) * 16384 + w * 1024); \
    GL_LDS(_s + 64 * 2048, smem + 65536 + (bb) * 32768 + (h) * 16384 + (8 + w) * 1024); }
#define RD_A(dst, bb, kk) { const char* _p = smem + (bb) * 32768 + aoff; \
    _Pragma("unroll") for (int f = 0; f < 8; ++f) \
        dst[f] = *(const s16x8*)(_p + f * 2048 + (colr ^ ((kk) << 6))); }
#define RD_B(dst, bb, kk) { const char* _p = smem + 65536 + (bb) * 32768 + boff; \
    _Pragma("unroll") for (int n = 0; n < 4; ++n) \
        dst[n] = *(const s16x8*)(_p + n * 2048 + (colr ^ ((kk) << 6))); }
#define MM16(fh, af, bf) { __builtin_amdgcn_s_setprio(1); \
    _Pragma("unroll") for (int f = 0; f < 4; ++f) \
        _Pragma("unroll") for (int n = 0; n < 4; ++n) \
            acc[(fh) * 4 + f][n] = __builtin_amdgcn_mfma_f32_16x16x32_bf16( \
                af[(fh) * 4 + f], bf[n], acc[(fh) * 4 + f][n], 0, 0, 0); \
    __builtin_amdgcn_s_setprio(0); }

template<int OUTF32>
__global__ __launch_bounds__(512) void gemm8(const ushort* __restrict__ A,
                                             const ushort* __restrict__ Bm,
                                             void* __restrict__ Cv, int N) {
    __shared__ char smem[131072];
    const int tid = threadIdx.x;
    const int w = tid >> 6, lane = tid & 63;
    const int wr = w >> 2, wc = w & 3;           // 2M x 4N waves
    const int l16 = lane & 15, lq = lane >> 4;

    // bijective XCD swizzle (gridDim.x % 8 == 0)
    const int nbn = N >> 8;
    const int cpx = gridDim.x >> 3;
    const int L = (blockIdx.x & 7) * cpx + (blockIdx.x >> 3);
    const int bm0 = (L / nbn) << 8, bn0 = (L % nbn) << 8;

    const ushort* Ab = A + (size_t)bm0 * 2048;
    const ushort* Bb = Bm + (size_t)bn0 * 2048;

    // stage per-lane offset: chunk rows w*8+(lane>>3), pre-swizzled column
    const int colu = (((lane & 7) ^ ((lane >> 3) & 7)) << 3);       // ushorts
    const u32 off0 = (u32)((w * 8 + (lane >> 3)) * 2048 + colu);
    // read addressing
    const int colr = (lq << 4) ^ ((l16 & 7) << 4);                  // bytes
    const int aoff = wr * 16384 + l16 * 128;
    const int boff = (wc >> 1) * 16384 + ((wc & 1) * 64 + l16) * 128;

    f32x4 acc[8][4] = {};
    s16x8 a0[8], a1[8], b0[4], b1[4];

    // prologue: t0 full + t1.A0,B0  (12 loads; allow last 4 outstanding)
    ST_A(0, 0, 0); ST_B(0, 0, 0); ST_A(0, 1, 0); ST_B(0, 1, 0);
    ST_A(1, 0, 64); ST_B(1, 0, 64);
    VMW4(); BAR();

    for (int i = 0; i < 16; ++i) {
        const int kc1 = ((2 * i + 1) & 31) * 64;
        const int kc2 = ((2 * i + 2) & 31) * 64;
        const int kc3 = ((2 * i + 3) & 31) * 64;
        // ---- tile 2i in buf0 ----
        RD_A(a0, 0, 0); RD_B(b0, 0, 0);
        ST_A(1, 1, kc1);                              // S1: t+1.A1
        BAR(); MM16(0, a0, b0); BAR();                // P1
        RD_A(a1, 0, 1); RD_B(b1, 0, 1);
        ST_B(1, 1, kc1);                              // S2: t+1.B1
        BAR(); MM16(0, a1, b1); LGKM0(); BAR();       // P2 (drain buf0 reads)
        ST_A(0, 0, kc2);                              // S3: t+2.A0
        BAR(); MM16(1, a0, b0); BAR();                // P3
        ST_B(0, 0, kc2);                              // S4: t+2.B0
        VMW4(); BAR(); MM16(1, a1, b1); BAR();        // P4
        // ---- tile 2i+1 in buf1 ----
        RD_A(a0, 1, 0); RD_B(b0, 1, 0);
        ST_A(0, 1, kc2);                              // S5: t+2.A1
        BAR(); MM16(0, a0, b0); BAR();                // P5
        RD_A(a1, 1, 1); RD_B(b1, 1, 1);
        ST_B(0, 1, kc2);                              // S6: t+2.B1
        BAR(); MM16(0, a1, b1); LGKM0(); BAR();       // P6 (drain buf1 reads)
        ST_A(1, 0, kc3);                              // S7: t+3.A0
        BAR(); MM16(1, a0, b0); BAR();                // P7
        ST_B(1, 0, kc3);                              // S8: t+3.B0
        VMW4(); BAR(); MM16(1, a1, b1); BAR();        // P8
    }

    // epilogue
    #pragma unroll
    for (int f = 0; f < 8; ++f)
        #pragma unroll
        for (int n = 0; n < 4; ++n) {
            int row = bm0 + wr * 128 + f * 16 + lq * 4;
            int col = bn0 + wc * 64 + n * 16 + l16;
            if (OUTF32) {
                float* C = (float*)Cv;
                #pragma unroll
                for (int r = 0; r < 4; ++r)
                    C[(size_t)(row + r) * N + col] = acc[f][n][r];
            } else {
                ushort* C = (ushort*)Cv;
                #pragma unroll
                for (int r = 0; r < 4; ++r)
                    C[(size_t)(row + r) * N + col] = f2bf(acc[f][n][r]);
            }
        }
}

// ---------------- Flash attention (v2) ----------------------------------
__global__ __launch_bounds__(256, 2) void attn_k(const ushort* __restrict__ qkv,
                                                 const ushort* __restrict__ vt,
                                                 ushort* __restrict__ aout) {
    extern __shared__ char asmem[];

    const int bid = blockIdx.x;
    const int L = (bid & 7) * 64 + (bid >> 3);
    const int qt = L & 15, bh = L >> 4;
    const int b = bh >> 4, h = bh & 15;
    const int tid = threadIdx.x;
    const int w = tid >> 6, lane = tid & 63;
    const int l16 = lane & 15, lq = lane >> 4;

    s16x8 qf[2][4];
    #pragma unroll
    for (int qb = 0; qb < 2; ++qb) {
        size_t qbase = (size_t)(b * SS + qt * 128 + w * 32 + qb * 16 + l16) * QKVN + h * HDD;
        #pragma unroll
        for (int kk = 0; kk < 4; ++kk)
            qf[qb][kk] = *(const s16x8*)(qkv + qbase + kk * 32 + lq * 8);
    }

    const ushort* ksrc[4];
    const ushort* vsrc[4];
    #pragma unroll
    for (int i = 0; i < 4; ++i) {
        int krow = w * 16 + i * 4 + (lane >> 4);
        int kcolb = ((lane & 15) * 16) ^ ((krow & 7) << 4);
        ksrc[i] = qkv + (size_t)(b * SS + krow) * QKVN + HIDD + h * HDD + kcolb / 2;
        int drow = w * 32 + i * 8 + (lane >> 3);
        int vcolb = ((lane & 7) * 16) ^ ((drow & 7) << 4);
        vsrc[i] = vt + ((size_t)(b * NHH + h) * HDD + drow) * SS + vcolb / 2;
    }

    f32x4 accO[2][8] = {};
    float mrow[2] = {-3e38f, -3e38f};
    float lrow[2] = {0.f, 0.f};

    char* Pb = asmem + 65536 + w * 4096;
    const int kswz = (l16 & 7) << 4;
    const int pswz = (l16 & 3) << 5;

    {
        char* kb = asmem + w * 4096;
        char* vb = asmem + 32768 + w * 4096;
        #pragma unroll
        for (int i = 0; i < 4; ++i) {
            GL_LDS(ksrc[i], kb + i * 1024); ksrc[i] += 64 * QKVN;
            GL_LDS(vsrc[i], vb + i * 1024); vsrc[i] += 64;
        }
    }
    __syncthreads();

    for (int t = 0; t < 32; ++t) {
        const int cur = t & 1;
        if (t < 31) {
            char* kb = asmem + (cur ^ 1) * 16384 + w * 4096;
            char* vb = asmem + 32768 + (cur ^ 1) * 16384 + w * 4096;
            #pragma unroll
            for (int i = 0; i < 4; ++i) {
                GL_LDS(ksrc[i], kb + i * 1024); ksrc[i] += 64 * QKVN;
                GL_LDS(vsrc[i], vb + i * 1024); vsrc[i] += 64;
            }
        }
        const char* Kb = asmem + cur * 16384;
        const char* Vb = asmem + 32768 + cur * 16384;

        f32x4 sc[2][4] = {};
        #pragma unroll
        for (int nb = 0; nb < 4; ++nb) {
            int rbase = (nb * 16 + l16) * 256;
            #pragma unroll
            for (int kk = 0; kk < 4; ++kk) {
                s16x8 kf = *(const s16x8*)(Kb + rbase + ((kk * 64 + lq * 16) ^ kswz));
                sc[0][nb] = __builtin_amdgcn_mfma_f32_16x16x32_bf16(kf, qf[0][kk], sc[0][nb], 0, 0, 0);
                sc[1][nb] = __builtin_amdgcn_mfma_f32_16x16x32_bf16(kf, qf[1][kk], sc[1][nb], 0, 0, 0);
            }
        }

        float scl[2];
        #pragma unroll
        for (int qb = 0; qb < 2; ++qb) {
            float m0 = fmaxf(fmaxf(sc[qb][0][0], sc[qb][0][1]), fmaxf(sc[qb][0][2], sc[qb][0][3]));
            #pragma unroll
            for (int nb = 1; nb < 4; ++nb)
                m0 = fmaxf(m0, fmaxf(fmaxf(sc[qb][nb][0], sc[qb][nb][1]),
                                     fmaxf(sc[qb][nb][2], sc[qb][nb][3])));
            m0 = fmaxf(m0, __shfl_xor(m0, 16));
            m0 = fmaxf(m0, __shfl_xor(m0, 32));
            float mnew = fmaxf(mrow[qb], m0);
            scl[qb] = __expf(mrow[qb] - mnew);
            mrow[qb] = mnew;
            float s = 0.f;
            #pragma unroll
            for (int nb = 0; nb < 4; ++nb)
                #pragma unroll
                for (int r = 0; r < 4; ++r) {
                    float pv = __expf(sc[qb][nb][r] - mnew);
                    sc[qb][nb][r] = pv;
                    s += pv;
                }
            s += __shfl_xor(s, 16);
            s += __shfl_xor(s, 32);
            lrow[qb] = lrow[qb] * scl[qb] + s;
        }
        #pragma unroll
        for (int r = 0; r < 4; ++r) {
            float s0 = __shfl(scl[0], lq * 4 + r);
            float s1 = __shfl(scl[1], lq * 4 + r);
            #pragma unroll
            for (int ob = 0; ob < 8; ++ob) {
                accO[0][ob][r] *= s0;
                accO[1][ob][r] *= s1;
            }
        }

        #pragma unroll
        for (int qb = 0; qb < 2; ++qb) {
            int qrow = (qb * 16 + l16) * 128;
            #pragma unroll
            for (int nb = 0; nb < 4; ++nb) {
                u32 lo = (u32)f2bf(sc[qb][nb][0]) | ((u32)f2bf(sc[qb][nb][1]) << 16);
                u32 hi = (u32)f2bf(sc[qb][nb][2]) | ((u32)f2bf(sc[qb][nb][3]) << 16);
                uint2 v2 = make_uint2(lo, hi);
                *(uint2*)(Pb + qrow + ((nb * 32 + lq * 8) ^ pswz)) = v2;
            }
        }

        #pragma unroll
        for (int kk2 = 0; kk2 < 2; ++kk2) {
            int cb = (kk2 * 64 + lq * 16);
            s16x8 pf0 = *(const s16x8*)(Pb + l16 * 128 + (cb ^ pswz));
            s16x8 pf1 = *(const s16x8*)(Pb + (16 + l16) * 128 + (cb ^ pswz));
            #pragma unroll
            for (int ob = 0; ob < 8; ++ob) {
                int d = ob * 16 + l16;
                s16x8 vf = *(const s16x8*)(Vb + d * 128 + (cb ^ ((d & 7) << 4)));
                accO[0][ob] = __builtin_amdgcn_mfma_f32_16x16x32_bf16(pf0, vf, accO[0][ob], 0, 0, 0);
                accO[1][ob] = __builtin_amdgcn_mfma_f32_16x16x32_bf16(pf1, vf, accO[1][ob], 0, 0, 0);
            }
        }
        __syncthreads();
    }

    float inv0 = 1.f / lrow[0], inv1 = 1.f / lrow[1];
    #pragma unroll
    for (int r = 0; r < 4; ++r) {
        float i0 = __shfl(inv0, lq * 4 + r);
        float i1 = __shfl(inv1, lq * 4 + r);
        int row0 = b * SS + qt * 128 + w * 32 + lq * 4 + r;
        #pragma unroll
        for (int ob = 0; ob < 8; ++ob) {
            int col = h * HDD + ob * 16 + l16;
            aout[(size_t)row0 * HIDD + col] = f2bf(accO[0][ob][r] * i0);
            aout[(size_t)(row0 + 16) * HIDD + col] = f2bf(accO[1][ob][r] * i1);
        }
    }
}

// ---------------- launch -------------------------------------------------
extern "C" void kernel_launch(void* const* d_in, const int* in_sizes, int n_in,
                              void* d_out, int out_size, void* d_ws, size_t ws_size,
                              hipStream_t stream) {
    const float* x     = (const float*)d_in[0];
    const float* w_qkv = (const float*)d_in[1];
    const float* w_out = (const float*)d_in[2];
    float* out = (float*)d_out;

    char* ws = (char*)d_ws;
    ushort* qkv_bf  = (ushort*)(ws);                        // 50,331,648 B
    ushort* xbf     = (ushort*)(ws + 50331648);             // 16,777,216 B (-> attn out)
    ushort* wq_bf   = (ushort*)(ws + 67108864);             // 25,165,824 B region
    ushort* vtbuf   = (ushort*)(ws + 67108864);             //   VT reuses it
    ushort* wout_bf = (ushort*)(ws + 67108864 + 16777216);  //   + w_out bf16
    float2* tab     = (float2*)(ws + 92274688);

    cvt_f32_bf16<<<2048, 256, 0, stream>>>(x, xbf, (NROWS * HIDD) / 4);
    cvt_f32_bf16<<<2048, 256, 0, stream>>>(w_qkv, wq_bf, (QKVN * HIDD) / 4);
    rope_table_k<<<(SS * 64) / 256, 256, 0, stream>>>(tab);

    // QKV projection: 8-phase 256^2 kernel, grid 16x24 = 384 blocks
    gemm8<0><<<(NROWS / 256) * (QKVN / 256), 512, 0, stream>>>(xbf, wq_bf, qkv_bf, QKVN);

    rope_apply_k<<<(NROWS * 2 * NHH * 64) / 256, 256, 0, stream>>>(qkv_bf, tab,
                                                                   out + (size_t)NROWS * HIDD);
    vtrans_k<<<2048, 256, 0, stream>>>(qkv_bf, vtbuf);
    cvt_f32_bf16<<<2048, 256, 0, stream>>>(w_out, wout_bf, (HIDD * HIDD) / 4);

    attn_k<<<512, 256, 81920, stream>>>(qkv_bf, vtbuf, xbf);

    gemm_bt<1><<<dim3(HIDD / 128, NROWS / 128), 256, 0, stream>>>(xbf, wout_bf, out,
                                                                  NROWS, HIDD, HIDD);
}

// Round 5
// 326.509 us; speedup vs baseline: 1.8634x; 1.0330x over previous
//
#include <hip/hip_runtime.h>
#include <hip/hip_bf16.h>
#include <stdint.h>

// Problem constants
#define BB 2
#define SS 2048
#define HIDD 2048
#define NHH 16
#define HDD 128
#define NROWS (BB*SS)        // 4096
#define QKVN (3*HIDD)        // 6144
// 1/sqrt(128) * log2(e): scores land in log2 domain -> exp2 in softmax
#define SCALE_QL2 (0.08838834764831845f * 1.4426950408889634f)

typedef float f32x4 __attribute__((ext_vector_type(4)));
typedef short s16x8 __attribute__((ext_vector_type(8)));
typedef uint32_t u32;
typedef __attribute__((address_space(1))) const u32 gau32;
typedef __attribute__((address_space(3))) u32 lau32;

__device__ __forceinline__ ushort f2bf(float f) {
    u32 u = __builtin_bit_cast(u32, f);
    u32 r = (u + 0x7fffu + ((u >> 16) & 1u)) >> 16;
    return (ushort)r;
}
__device__ __forceinline__ float bf2f(ushort h) {
    u32 u = ((u32)h) << 16;
    return __builtin_bit_cast(float, u);
}
__device__ __forceinline__ u32 cvtpk(float lo, float hi) {
    u32 r;
    asm("v_cvt_pk_bf16_f32 %0, %1, %2" : "=v"(r) : "v"(lo), "v"(hi));
    return r;
}
#define EXP2(x) __builtin_amdgcn_exp2f(x)

// ---------------- fp32 -> bf16 convert (vectorized, grid-stride) ----------
__global__ __launch_bounds__(256) void cvt_f32_bf16(const float* __restrict__ in,
                                                    ushort* __restrict__ out, int n4) {
    int i = blockIdx.x * 256 + threadIdx.x;
    int stride = gridDim.x * 256;
    for (; i < n4; i += stride) {
        float4 v = ((const float4*)in)[i];
        ushort4 o;
        o.x = f2bf(v.x); o.y = f2bf(v.y); o.z = f2bf(v.z); o.w = f2bf(v.w);
        ((ushort4*)out)[i] = o;
    }
}

// ---------------- RoPE cos/sin table: [2048][64] float2 ------------------
__global__ __launch_bounds__(256) void rope_table_k(float2* __restrict__ tab) {
    int idx = blockIdx.x * 256 + threadIdx.x;
    if (idx >= SS * 64) return;
    int j = idx & 63;
    int s = idx >> 6;
    float e = -(float)j * (13.287712379549449f / 64.0f);
    float inv = exp2f(e);
    float ang = (float)s * inv;
    float sv, cv;
    sincosf(ang, &sv, &cv);
    tab[idx] = make_float2(cv, sv);
}

// ---------------- RoPE apply in-place on bf16 QKV; emit fp32 K out -------
__global__ __launch_bounds__(256) void rope_apply_k(ushort* __restrict__ qkv,
                                                    const float2* __restrict__ tab,
                                                    float* __restrict__ kout) {
    int p = blockIdx.x * 256 + threadIdx.x;
    if (p >= NROWS * 2 * NHH * 64) return;
    int j  = p & 63;
    int h  = (p >> 6) & 15;
    int w  = (p >> 10) & 1;   // 0=q, 1=k
    int bs = p >> 11;
    int s  = bs & (SS - 1);
    size_t off = (size_t)bs * QKVN + (size_t)w * HIDD + h * HDD + 2 * j;
    u32 pr = *(const u32*)(qkv + off);
    float x1 = bf2f((ushort)(pr & 0xffffu));
    float x2 = bf2f((ushort)(pr >> 16));
    float2 cs = tab[s * 64 + j];
    float r1 = x1 * cs.x - x2 * cs.y;
    float r2 = x1 * cs.y + x2 * cs.x;
    if (w == 0) {            // fold score scale AND log2(e) into Q
        r1 *= SCALE_QL2; r2 *= SCALE_QL2;
    } else {                 // K: also write fp32 output (unscaled)
        float* ko = kout + ((size_t)bs * NHH + h) * HDD + 2 * j;
        ko[0] = r1; ko[1] = r2;
    }
    u32 op = (u32)f2bf(r1) | ((u32)f2bf(r2) << 16);
    *(u32*)(qkv + off) = op;
}

// ---------------- V transpose: qkv V section -> VT[b][h][d][s] -----------
__global__ __launch_bounds__(256) void vtrans_k(const ushort* __restrict__ qkv,
                                                ushort* __restrict__ vt) {
    __shared__ ushort tile[64 * 66];
    int bid = blockIdx.x;              // 2048 = 32 bh * 32 st * 2 dt
    int dt = bid & 1, st = (bid >> 1) & 31, bh = bid >> 6;
    int b = bh >> 4, h = bh & 15;
    int s0 = st * 64, d0 = dt * 64;
    int tid = threadIdx.x;
    #pragma unroll
    for (int i = 0; i < 2; ++i) {
        int idx = tid + i * 256;
        int row = idx >> 3, c8 = idx & 7;
        const ushort* src = qkv + (size_t)(b * SS + s0 + row) * QKVN + 2 * HIDD + h * HDD + d0 + c8 * 8;
        uint4 v = *(const uint4*)src;
        const u32* vw = (const u32*)&v;
        u32* dst = (u32*)((char*)tile + row * 132 + c8 * 16);
        dst[0] = vw[0]; dst[1] = vw[1]; dst[2] = vw[2]; dst[3] = vw[3];
    }
    __syncthreads();
    #pragma unroll
    for (int i = 0; i < 2; ++i) {
        int idx = tid + i * 256;
        int d = idx >> 3, sc8 = idx & 7;
        u32 wv[4];
        #pragma unroll
        for (int k = 0; k < 4; ++k) {
            ushort a = tile[(sc8 * 8 + 2 * k) * 66 + d];
            ushort c = tile[(sc8 * 8 + 2 * k + 1) * 66 + d];
            wv[k] = (u32)a | ((u32)c << 16);
        }
        ushort* dst = vt + ((size_t)(b * NHH + h) * HDD + d0 + d) * SS + s0 + sc8 * 8;
        *(uint4*)dst = *(const uint4*)wv;
    }
}

// ---------------- old 128x128 2-phase GEMM (kept for output projection) --
template<int OUTF32>
__global__ __launch_bounds__(256) void gemm_bt(const ushort* __restrict__ A,
                                               const ushort* __restrict__ Bm,
                                               void* __restrict__ Cv,
                                               int M, int N, int K) {
    __shared__ ushort Alds[128 * 32];
    __shared__ ushort Blds[128 * 32];
    const int bn = blockIdx.x, bm = blockIdx.y;
    const int tid = threadIdx.x;
    const int w = tid >> 6, lane = tid & 63;
    const int wr = w >> 1, wc = w & 1;
    const int l16 = lane & 15, lq = lane >> 4;
    const int bm0 = bm * 128, bn0 = bn * 128;

    f32x4 acc[4][4] = {};

    for (int k0 = 0; k0 < K; k0 += 32) {
        __syncthreads();
        #pragma unroll
        for (int q = 0; q < 2; ++q) {
            int qq = w + q * 4;
            const ushort* ga = A + (size_t)(bm0 + qq * 16 + (lane >> 2)) * K + k0 + (lane & 3) * 8;
            __builtin_amdgcn_global_load_lds((gau32*)ga, (lau32*)(Alds + qq * 512), 16, 0, 0);
            const ushort* gb = Bm + (size_t)(bn0 + qq * 16 + (lane >> 2)) * K + k0 + (lane & 3) * 8;
            __builtin_amdgcn_global_load_lds((gau32*)gb, (lau32*)(Blds + qq * 512), 16, 0, 0);
        }
        __syncthreads();
        s16x8 af[4], bf[4];
        #pragma unroll
        for (int m = 0; m < 4; ++m)
            af[m] = *(const s16x8*)(Alds + (wr * 64 + m * 16 + l16) * 32 + lq * 8);
        #pragma unroll
        for (int n = 0; n < 4; ++n)
            bf[n] = *(const s16x8*)(Blds + (wc * 64 + n * 16 + l16) * 32 + lq * 8);
        #pragma unroll
        for (int m = 0; m < 4; ++m)
            #pragma unroll
            for (int n = 0; n < 4; ++n)
                acc[m][n] = __builtin_amdgcn_mfma_f32_16x16x32_bf16(af[m], bf[n], acc[m][n], 0, 0, 0);
    }

    #pragma unroll
    for (int m = 0; m < 4; ++m)
        #pragma unroll
        for (int n = 0; n < 4; ++n) {
            int row = bm0 + wr * 64 + m * 16 + lq * 4;
            int col = bn0 + wc * 64 + n * 16 + l16;
            if (OUTF32) {
                float* C = (float*)Cv;
                #pragma unroll
                for (int r = 0; r < 4; ++r)
                    C[(size_t)(row + r) * N + col] = acc[m][n][r];
            } else {
                ushort* C = (ushort*)Cv;
                #pragma unroll
                for (int r = 0; r < 4; ++r)
                    C[(size_t)(row + r) * N + col] = f2bf(acc[m][n][r]);
            }
        }
}

// ---------------- 256x256 8-phase GEMM, C = A * B^T, K=2048 --------------
#define GL_LDS(s, d) __builtin_amdgcn_global_load_lds((gau32*)(s), (lau32*)(d), 16, 0, 0)
#define BAR() __builtin_amdgcn_s_barrier()
#define VMW4() { asm volatile("s_waitcnt vmcnt(4)" ::: "memory"); __builtin_amdgcn_sched_barrier(0); }
#define LGKM0() { asm volatile("s_waitcnt lgkmcnt(0)" ::: "memory"); __builtin_amdgcn_sched_barrier(0); }

#define ST_A(bb, h, kc) { \
    const ushort* _s = Ab + (size_t)((h) * 128 * 2048 + (kc)) + off0; \
    GL_LDS(_s, smem + (bb) * 32768 + (h) * 16384 + w * 1024); \
    GL_LDS(_s + 64 * 2048, smem + (bb) * 32768 + (h) * 16384 + (8 + w) * 1024); }
#define ST_B(bb, h, kc) { \
    const ushort* _s = Bb + (size_t)((h) * 128 * 2048 + (kc)) + off0; \
    GL_LDS(_s, smem + 65536 + (bb) * 32768 + (h) * 16384 + w * 1024); \
    GL_LDS(_s + 64 * 2048, smem + 65536 + (bb) * 32768 + (h) * 16384 + (8 + w) * 1024); }
#define RD_A(dst, bb, kk) { const char* _p = smem + (bb) * 32768 + aoff; \
    _Pragma("unroll") for (int f = 0; f < 8; ++f) \
        dst[f] = *(const s16x8*)(_p + f * 2048 + (colr ^ ((kk) << 6))); }
#define RD_B(dst, bb, kk) { const char* _p = smem + 65536 + (bb) * 32768 + boff; \
    _Pragma("unroll") for (int n = 0; n < 4; ++n) \
        dst[n] = *(const s16x8*)(_p + n * 2048 + (colr ^ ((kk) << 6))); }
#define MM16(fh, af, bf) { __builtin_amdgcn_s_setprio(1); \
    _Pragma("unroll") for (int f = 0; f < 4; ++f) \
        _Pragma("unroll") for (int n = 0; n < 4; ++n) \
            acc[(fh) * 4 + f][n] = __builtin_amdgcn_mfma_f32_16x16x32_bf16( \
                af[(fh) * 4 + f], bf[n], acc[(fh) * 4 + f][n], 0, 0, 0); \
    __builtin_amdgcn_s_setprio(0); }

template<int OUTF32>
__global__ __launch_bounds__(512) void gemm8(const ushort* __restrict__ A,
                                             const ushort* __restrict__ Bm,
                                             void* __restrict__ Cv, int N) {
    __shared__ char smem[131072];
    const int tid = threadIdx.x;
    const int w = tid >> 6, lane = tid & 63;
    const int wr = w >> 2, wc = w & 3;           // 2M x 4N waves
    const int l16 = lane & 15, lq = lane >> 4;

    const int nbn = N >> 8;
    const int cpx = gridDim.x >> 3;
    const int L = (blockIdx.x & 7) * cpx + (blockIdx.x >> 3);
    const int bm0 = (L / nbn) << 8, bn0 = (L % nbn) << 8;

    const ushort* Ab = A + (size_t)bm0 * 2048;
    const ushort* Bb = Bm + (size_t)bn0 * 2048;

    const int colu = (((lane & 7) ^ ((lane >> 3) & 7)) << 3);       // ushorts
    const u32 off0 = (u32)((w * 8 + (lane >> 3)) * 2048 + colu);
    const int colr = (lq << 4) ^ ((l16 & 7) << 4);                  // bytes
    const int aoff = wr * 16384 + l16 * 128;
    const int boff = (wc >> 1) * 16384 + ((wc & 1) * 64 + l16) * 128;

    f32x4 acc[8][4] = {};
    s16x8 a0[8], a1[8], b0[4], b1[4];

    ST_A(0, 0, 0); ST_B(0, 0, 0); ST_A(0, 1, 0); ST_B(0, 1, 0);
    ST_A(1, 0, 64); ST_B(1, 0, 64);
    VMW4(); BAR();

    for (int i = 0; i < 16; ++i) {
        const int kc1 = ((2 * i + 1) & 31) * 64;
        const int kc2 = ((2 * i + 2) & 31) * 64;
        const int kc3 = ((2 * i + 3) & 31) * 64;
        RD_A(a0, 0, 0); RD_B(b0, 0, 0);
        ST_A(1, 1, kc1);
        BAR(); MM16(0, a0, b0); BAR();
        RD_A(a1, 0, 1); RD_B(b1, 0, 1);
        ST_B(1, 1, kc1);
        BAR(); MM16(0, a1, b1); LGKM0(); BAR();
        ST_A(0, 0, kc2);
        BAR(); MM16(1, a0, b0); BAR();
        ST_B(0, 0, kc2);
        VMW4(); BAR(); MM16(1, a1, b1); BAR();
        RD_A(a0, 1, 0); RD_B(b0, 1, 0);
        ST_A(0, 1, kc2);
        BAR(); MM16(0, a0, b0); BAR();
        RD_A(a1, 1, 1); RD_B(b1, 1, 1);
        ST_B(0, 1, kc2);
        BAR(); MM16(0, a1, b1); LGKM0(); BAR();
        ST_A(1, 0, kc3);
        BAR(); MM16(1, a0, b0); BAR();
        ST_B(1, 0, kc3);
        VMW4(); BAR(); MM16(1, a1, b1); BAR();
    }

    #pragma unroll
    for (int f = 0; f < 8; ++f)
        #pragma unroll
        for (int n = 0; n < 4; ++n) {
            int row = bm0 + wr * 128 + f * 16 + lq * 4;
            int col = bn0 + wc * 64 + n * 16 + l16;
            if (OUTF32) {
                float* C = (float*)Cv;
                #pragma unroll
                for (int r = 0; r < 4; ++r)
                    C[(size_t)(row + r) * N + col] = acc[f][n][r];
            } else {
                ushort* C = (ushort*)Cv;
                #pragma unroll
                for (int r = 0; r < 4; ++r)
                    C[(size_t)(row + r) * N + col] = f2bf(acc[f][n][r]);
            }
        }
}

// ---------------- Flash attention (v3: log2 softmax, defer-max, cvt_pk) --
__global__ __launch_bounds__(256, 2) void attn_k(const ushort* __restrict__ qkv,
                                                 const ushort* __restrict__ vt,
                                                 ushort* __restrict__ aout) {
    extern __shared__ char asmem[];

    const int bid = blockIdx.x;
    const int L = (bid & 7) * 64 + (bid >> 3);
    const int qt = L & 15, bh = L >> 4;
    const int b = bh >> 4, h = bh & 15;
    const int tid = threadIdx.x;
    const int w = tid >> 6, lane = tid & 63;
    const int l16 = lane & 15, lq = lane >> 4;

    s16x8 qf[2][4];
    #pragma unroll
    for (int qb = 0; qb < 2; ++qb) {
        size_t qbase = (size_t)(b * SS + qt * 128 + w * 32 + qb * 16 + l16) * QKVN + h * HDD;
        #pragma unroll
        for (int kk = 0; kk < 4; ++kk)
            qf[qb][kk] = *(const s16x8*)(qkv + qbase + kk * 32 + lq * 8);
    }

    const ushort* ksrc[4];
    const ushort* vsrc[4];
    #pragma unroll
    for (int i = 0; i < 4; ++i) {
        int krow = w * 16 + i * 4 + (lane >> 4);
        int kcolb = ((lane & 15) * 16) ^ ((krow & 7) << 4);
        ksrc[i] = qkv + (size_t)(b * SS + krow) * QKVN + HIDD + h * HDD + kcolb / 2;
        int drow = w * 32 + i * 8 + (lane >> 3);
        int vcolb = ((lane & 7) * 16) ^ ((drow & 7) << 4);
        vsrc[i] = vt + ((size_t)(b * NHH + h) * HDD + drow) * SS + vcolb / 2;
    }

    f32x4 accO[2][8] = {};
    float mrow[2] = {-3e38f, -3e38f};
    float lrow[2] = {0.f, 0.f};

    char* Pb = asmem + 65536 + w * 4096;
    const int kswz = (l16 & 7) << 4;
    const int pswz = (l16 & 3) << 5;

    {
        char* kb = asmem + w * 4096;
        char* vb = asmem + 32768 + w * 4096;
        #pragma unroll
        for (int i = 0; i < 4; ++i) {
            GL_LDS(ksrc[i], kb + i * 1024); ksrc[i] += 64 * QKVN;
            GL_LDS(vsrc[i], vb + i * 1024); vsrc[i] += 64;
        }
    }
    __syncthreads();

    for (int t = 0; t < 32; ++t) {
        const int cur = t & 1;
        if (t < 31) {
            char* kb = asmem + (cur ^ 1) * 16384 + w * 4096;
            char* vb = asmem + 32768 + (cur ^ 1) * 16384 + w * 4096;
            #pragma unroll
            for (int i = 0; i < 4; ++i) {
                GL_LDS(ksrc[i], kb + i * 1024); ksrc[i] += 64 * QKVN;
                GL_LDS(vsrc[i], vb + i * 1024); vsrc[i] += 64;
            }
        }
        const char* Kb = asmem + cur * 16384;
        const char* Vb = asmem + 32768 + cur * 16384;

        // S^T = K . Q  (scores already in log2 domain via Q pre-scale)
        f32x4 sc[2][4] = {};
        #pragma unroll
        for (int nb = 0; nb < 4; ++nb) {
            int rbase = (nb * 16 + l16) * 256;
            #pragma unroll
            for (int kk = 0; kk < 4; ++kk) {
                s16x8 kf = *(const s16x8*)(Kb + rbase + ((kk * 64 + lq * 16) ^ kswz));
                sc[0][nb] = __builtin_amdgcn_mfma_f32_16x16x32_bf16(kf, qf[0][kk], sc[0][nb], 0, 0, 0);
                sc[1][nb] = __builtin_amdgcn_mfma_f32_16x16x32_bf16(kf, qf[1][kk], sc[1][nb], 0, 0, 0);
            }
        }

        // online softmax with defer-max (T13): row = q = qb*16+l16
        float pmax[2];
        #pragma unroll
        for (int qb = 0; qb < 2; ++qb) {
            float m0 = fmaxf(fmaxf(fmaxf(sc[qb][0][0], sc[qb][0][1]), fmaxf(sc[qb][0][2], sc[qb][0][3])),
                             fmaxf(fmaxf(sc[qb][1][0], sc[qb][1][1]), fmaxf(sc[qb][1][2], sc[qb][1][3])));
            m0 = fmaxf(m0, fmaxf(fmaxf(fmaxf(sc[qb][2][0], sc[qb][2][1]), fmaxf(sc[qb][2][2], sc[qb][2][3])),
                                 fmaxf(fmaxf(sc[qb][3][0], sc[qb][3][1]), fmaxf(sc[qb][3][2], sc[qb][3][3]))));
            m0 = fmaxf(m0, __shfl_xor(m0, 16));
            m0 = fmaxf(m0, __shfl_xor(m0, 32));
            pmax[qb] = m0;
        }
        #pragma unroll
        for (int qb = 0; qb < 2; ++qb) {
            if (__all(pmax[qb] - mrow[qb] <= 8.0f)) {
                // defer: keep old max, P bounded by 2^8; no accO rescale
                float mm = mrow[qb];
                float s = 0.f;
                #pragma unroll
                for (int nb = 0; nb < 4; ++nb)
                    #pragma unroll
                    for (int r = 0; r < 4; ++r) {
                        float pv = EXP2(sc[qb][nb][r] - mm);
                        sc[qb][nb][r] = pv;
                        s += pv;
                    }
                s += __shfl_xor(s, 16);
                s += __shfl_xor(s, 32);
                lrow[qb] += s;
            } else {
                float mnew = fmaxf(mrow[qb], pmax[qb]);
                float sclv = EXP2(mrow[qb] - mnew);
                mrow[qb] = mnew;
                float s = 0.f;
                #pragma unroll
                for (int nb = 0; nb < 4; ++nb)
                    #pragma unroll
                    for (int r = 0; r < 4; ++r) {
                        float pv = EXP2(sc[qb][nb][r] - mnew);
                        sc[qb][nb][r] = pv;
                        s += pv;
                    }
                s += __shfl_xor(s, 16);
                s += __shfl_xor(s, 32);
                lrow[qb] = lrow[qb] * sclv + s;
                #pragma unroll
                for (int r = 0; r < 4; ++r) {
                    float sr = __shfl(sclv, lq * 4 + r);
                    #pragma unroll
                    for (int ob = 0; ob < 8; ++ob)
                        accO[qb][ob][r] *= sr;
                }
            }
        }

        // P -> per-wave swizzled LDS via v_cvt_pk_bf16_f32
        #pragma unroll
        for (int qb = 0; qb < 2; ++qb) {
            int qrow = (qb * 16 + l16) * 128;
            #pragma unroll
            for (int nb = 0; nb < 4; ++nb) {
                uint2 v2 = make_uint2(cvtpk(sc[qb][nb][0], sc[qb][nb][1]),
                                      cvtpk(sc[qb][nb][2], sc[qb][nb][3]));
                *(uint2*)(Pb + qrow + ((nb * 32 + lq * 8) ^ pswz)) = v2;
            }
        }

        // O += P . V
        #pragma unroll
        for (int kk2 = 0; kk2 < 2; ++kk2) {
            int cb = (kk2 * 64 + lq * 16);
            s16x8 pf0 = *(const s16x8*)(Pb + l16 * 128 + (cb ^ pswz));
            s16x8 pf1 = *(const s16x8*)(Pb + (16 + l16) * 128 + (cb ^ pswz));
            #pragma unroll
            for (int ob = 0; ob < 8; ++ob) {
                int d = ob * 16 + l16;
                s16x8 vf = *(const s16x8*)(Vb + d * 128 + (cb ^ ((d & 7) << 4)));
                accO[0][ob] = __builtin_amdgcn_mfma_f32_16x16x32_bf16(pf0, vf, accO[0][ob], 0, 0, 0);
                accO[1][ob] = __builtin_amdgcn_mfma_f32_16x16x32_bf16(pf1, vf, accO[1][ob], 0, 0, 0);
            }
        }
        __syncthreads();
    }

    float inv0 = 1.f / lrow[0], inv1 = 1.f / lrow[1];
    #pragma unroll
    for (int r = 0; r < 4; ++r) {
        float i0 = __shfl(inv0, lq * 4 + r);
        float i1 = __shfl(inv1, lq * 4 + r);
        int row0 = b * SS + qt * 128 + w * 32 + lq * 4 + r;
        #pragma unroll
        for (int ob = 0; ob < 8; ++ob) {
            int col = h * HDD + ob * 16 + l16;
            aout[(size_t)row0 * HIDD + col] = f2bf(accO[0][ob][r] * i0);
            aout[(size_t)(row0 + 16) * HIDD + col] = f2bf(accO[1][ob][r] * i1);
        }
    }
}

// ---------------- launch -------------------------------------------------
extern "C" void kernel_launch(void* const* d_in, const int* in_sizes, int n_in,
                              void* d_out, int out_size, void* d_ws, size_t ws_size,
                              hipStream_t stream) {
    const float* x     = (const float*)d_in[0];
    const float* w_qkv = (const float*)d_in[1];
    const float* w_out = (const float*)d_in[2];
    float* out = (float*)d_out;

    char* ws = (char*)d_ws;
    ushort* qkv_bf  = (ushort*)(ws);
    ushort* xbf     = (ushort*)(ws + 50331648);
    ushort* wq_bf   = (ushort*)(ws + 67108864);
    ushort* vtbuf   = (ushort*)(ws + 67108864);
    ushort* wout_bf = (ushort*)(ws + 67108864 + 16777216);
    float2* tab     = (float2*)(ws + 92274688);

    cvt_f32_bf16<<<2048, 256, 0, stream>>>(x, xbf, (NROWS * HIDD) / 4);
    cvt_f32_bf16<<<2048, 256, 0, stream>>>(w_qkv, wq_bf, (QKVN * HIDD) / 4);
    rope_table_k<<<(SS * 64) / 256, 256, 0, stream>>>(tab);

    gemm8<0><<<(NROWS / 256) * (QKVN / 256), 512, 0, stream>>>(xbf, wq_bf, qkv_bf, QKVN);

    rope_apply_k<<<(NROWS * 2 * NHH * 64) / 256, 256, 0, stream>>>(qkv_bf, tab,
                                                                   out + (size_t)NROWS * HIDD);
    vtrans_k<<<2048, 256, 0, stream>>>(qkv_bf, vtbuf);
    cvt_f32_bf16<<<2048, 256, 0, stream>>>(w_out, wout_bf, (HIDD * HIDD) / 4);

    attn_k<<<512, 256, 81920, stream>>>(qkv_bf, vtbuf, xbf);

    gemm_bt<1><<<dim3(HIDD / 128, NROWS / 128), 256, 0, stream>>>(xbf, wout_bf, out,
                                                                  NROWS, HIDD, HIDD);
}

// Round 6
// 293.570 us; speedup vs baseline: 2.0725x; 1.1122x over previous
//
#include <hip/hip_runtime.h>
#include <hip/hip_bf16.h>
#include <stdint.h>

// Problem constants
#define BB 2
#define SS 2048
#define HIDD 2048
#define NHH 16
#define HDD 128
#define NROWS (BB*SS)        // 4096
#define QKVN (3*HIDD)        // 6144
// 1/sqrt(128) * log2(e): scores land in log2 domain -> exp2 in softmax
#define SCALE_QL2 (0.08838834764831845f * 1.4426950408889634f)

typedef float f32x4 __attribute__((ext_vector_type(4)));
typedef short s16x8 __attribute__((ext_vector_type(8)));
typedef uint32_t u32;
typedef __attribute__((address_space(1))) const u32 gau32;
typedef __attribute__((address_space(3))) u32 lau32;

__device__ __forceinline__ ushort f2bf(float f) {
    u32 u = __builtin_bit_cast(u32, f);
    u32 r = (u + 0x7fffu + ((u >> 16) & 1u)) >> 16;
    return (ushort)r;
}
__device__ __forceinline__ float bf2f(ushort h) {
    u32 u = ((u32)h) << 16;
    return __builtin_bit_cast(float, u);
}
__device__ __forceinline__ u32 cvtpk(float lo, float hi) {
    u32 r;
    asm("v_cvt_pk_bf16_f32 %0, %1, %2" : "=v"(r) : "v"(lo), "v"(hi));
    return r;
}
#define EXP2(x) __builtin_amdgcn_exp2f(x)

#define GL_LDS(s, d) __builtin_amdgcn_global_load_lds((gau32*)(s), (lau32*)(d), 16, 0, 0)
#define BAR() __builtin_amdgcn_s_barrier()
#define SCB() __builtin_amdgcn_sched_barrier(0)
#define VMW(n) { asm volatile("s_waitcnt vmcnt(" #n ")" ::: "memory"); SCB(); }

// ---------------- fp32 -> bf16 convert (vectorized, grid-stride) ----------
__global__ __launch_bounds__(256) void cvt_f32_bf16(const float* __restrict__ in,
                                                    ushort* __restrict__ out, int n4) {
    int i = blockIdx.x * 256 + threadIdx.x;
    int stride = gridDim.x * 256;
    for (; i < n4; i += stride) {
        float4 v = ((const float4*)in)[i];
        ushort4 o;
        o.x = f2bf(v.x); o.y = f2bf(v.y); o.z = f2bf(v.z); o.w = f2bf(v.w);
        ((ushort4*)out)[i] = o;
    }
}

// ---------------- RoPE cos/sin table: [2048][64] float2 ------------------
__global__ __launch_bounds__(256) void rope_table_k(float2* __restrict__ tab) {
    int idx = blockIdx.x * 256 + threadIdx.x;
    if (idx >= SS * 64) return;
    int j = idx & 63;
    int s = idx >> 6;
    float e = -(float)j * (13.287712379549449f / 64.0f);
    float inv = exp2f(e);
    float ang = (float)s * inv;
    float sv, cv;
    sincosf(ang, &sv, &cv);
    tab[idx] = make_float2(cv, sv);
}

// ---------------- RoPE apply in-place on bf16 QKV; emit fp32 K out -------
__global__ __launch_bounds__(256) void rope_apply_k(ushort* __restrict__ qkv,
                                                    const float2* __restrict__ tab,
                                                    float* __restrict__ kout) {
    int p = blockIdx.x * 256 + threadIdx.x;
    if (p >= NROWS * 2 * NHH * 64) return;
    int j  = p & 63;
    int h  = (p >> 6) & 15;
    int w  = (p >> 10) & 1;   // 0=q, 1=k
    int bs = p >> 11;
    int s  = bs & (SS - 1);
    size_t off = (size_t)bs * QKVN + (size_t)w * HIDD + h * HDD + 2 * j;
    u32 pr = *(const u32*)(qkv + off);
    float x1 = bf2f((ushort)(pr & 0xffffu));
    float x2 = bf2f((ushort)(pr >> 16));
    float2 cs = tab[s * 64 + j];
    float r1 = x1 * cs.x - x2 * cs.y;
    float r2 = x1 * cs.y + x2 * cs.x;
    if (w == 0) {            // fold score scale AND log2(e) into Q
        r1 *= SCALE_QL2; r2 *= SCALE_QL2;
    } else {                 // K: also write fp32 output (unscaled)
        float* ko = kout + ((size_t)bs * NHH + h) * HDD + 2 * j;
        ko[0] = r1; ko[1] = r2;
    }
    u32 op = (u32)f2bf(r1) | ((u32)f2bf(r2) << 16);
    *(u32*)(qkv + off) = op;
}

// ---------------- V transpose: qkv V section -> VT[b][h][d][s] -----------
__global__ __launch_bounds__(256) void vtrans_k(const ushort* __restrict__ qkv,
                                                ushort* __restrict__ vt) {
    __shared__ ushort tile[64 * 66];
    int bid = blockIdx.x;              // 2048 = 32 bh * 32 st * 2 dt
    int dt = bid & 1, st = (bid >> 1) & 31, bh = bid >> 6;
    int b = bh >> 4, h = bh & 15;
    int s0 = st * 64, d0 = dt * 64;
    int tid = threadIdx.x;
    #pragma unroll
    for (int i = 0; i < 2; ++i) {
        int idx = tid + i * 256;
        int row = idx >> 3, c8 = idx & 7;
        const ushort* src = qkv + (size_t)(b * SS + s0 + row) * QKVN + 2 * HIDD + h * HDD + d0 + c8 * 8;
        uint4 v = *(const uint4*)src;
        const u32* vw = (const u32*)&v;
        u32* dst = (u32*)((char*)tile + row * 132 + c8 * 16);
        dst[0] = vw[0]; dst[1] = vw[1]; dst[2] = vw[2]; dst[3] = vw[3];
    }
    __syncthreads();
    #pragma unroll
    for (int i = 0; i < 2; ++i) {
        int idx = tid + i * 256;
        int d = idx >> 3, sc8 = idx & 7;
        u32 wv[4];
        #pragma unroll
        for (int k = 0; k < 4; ++k) {
            ushort a = tile[(sc8 * 8 + 2 * k) * 66 + d];
            ushort c = tile[(sc8 * 8 + 2 * k + 1) * 66 + d];
            wv[k] = (u32)a | ((u32)c << 16);
        }
        ushort* dst = vt + ((size_t)(b * NHH + h) * HDD + d0 + d) * SS + s0 + sc8 * 8;
        *(uint4*)dst = *(const uint4*)wv;
    }
}

// ---------------- 128x256-tile GEMM, C = A * B^T, K=2048 -----------------
// 8 waves (2M x 4N), per-wave out 64x64, BK=64, LDS 96KB double-buffered.
// QKV: 768 blocks = 3/CU exact; proj: 256 blocks = 1/CU exact (100% balance).
// Counted vmcnt(2) pipeline; compiler-managed lgkm waits; zero-conflict
// XOR swizzle (slot s holds k-chunk s^(row&7)), same scheme as before.
#define SA2(bb, kc) { const ushort* _s = Ab + (size_t)(kc) + off0; \
    GL_LDS(_s,            smem + (bb) * 49152 + w * 1024); \
    GL_LDS(_s + 64 * 2048, smem + (bb) * 49152 + 8192 + w * 1024); }
#define SB4(bb, kc) { const ushort* _s = Bb + (size_t)(kc) + off0; \
    GL_LDS(_s,             smem + (bb) * 49152 + 16384 + w * 1024); \
    GL_LDS(_s + 64 * 2048,  smem + (bb) * 49152 + 24576 + w * 1024); \
    GL_LDS(_s + 128 * 2048, smem + (bb) * 49152 + 32768 + w * 1024); \
    GL_LDS(_s + 192 * 2048, smem + (bb) * 49152 + 40960 + w * 1024); }
#define RDA(dst, bb, kk) { const char* _p = smem + (bb) * 49152 + aoff; \
    _Pragma("unroll") for (int f = 0; f < 4; ++f) \
        dst[f] = *(const s16x8*)(_p + f * 2048 + (colr ^ ((kk) << 6))); }
#define RDB(dst, bb, kk) { const char* _p = smem + (bb) * 49152 + 16384 + boff; \
    _Pragma("unroll") for (int n = 0; n < 4; ++n) \
        dst[n] = *(const s16x8*)(_p + n * 2048 + (colr ^ ((kk) << 6))); }
#define MMX(aa, bb2) { __builtin_amdgcn_s_setprio(1); \
    _Pragma("unroll") for (int f = 0; f < 4; ++f) \
        _Pragma("unroll") for (int n = 0; n < 4; ++n) \
            acc[f][n] = __builtin_amdgcn_mfma_f32_16x16x32_bf16( \
                aa[f], bb2[n], acc[f][n], 0, 0, 0); \
    __builtin_amdgcn_s_setprio(0); }

template<int OUTF32>
__global__ __launch_bounds__(512) void gemm128(const ushort* __restrict__ A,
                                               const ushort* __restrict__ Bm,
                                               void* __restrict__ Cv, int N) {
    __shared__ char smem[98304];
    const int tid = threadIdx.x;
    const int w = tid >> 6, lane = tid & 63;
    const int wr = w >> 2, wc = w & 3;           // 2M x 4N waves
    const int l16 = lane & 15, lq = lane >> 4;

    // bijective XCD swizzle (gridDim.x % 8 == 0)
    const int nbn = N >> 8;
    const int cpx = gridDim.x >> 3;
    const int L = (blockIdx.x & 7) * cpx + (blockIdx.x >> 3);
    const int bm0 = (L / nbn) << 7, bn0 = (L % nbn) << 8;

    const ushort* Ab = A + (size_t)bm0 * 2048;
    const ushort* Bb = Bm + (size_t)bn0 * 2048;

    // stage: rows chunk*64 + w*8 + (lane>>3), pre-swizzled column
    const int colu = ((lane & 7) ^ ((lane >> 3) & 7)) << 3;         // ushorts
    const u32 off0 = (u32)((w * 8 + (lane >> 3)) * 2048 + colu);
    // read addressing
    const int colr = (lq << 4) ^ ((l16 & 7) << 4);                  // bytes
    const int aoff = wr * 8192 + l16 * 128;
    const int boff = wc * 8192 + l16 * 128;

    f32x4 acc[4][4] = {};
    s16x8 a0[4], a1[4], b0[4], b1[4];

    // prologue: stage tile 0 into buf0 (6 loads)
    SA2(0, 0); SB4(0, 0);

    for (int t = 0; t < 32; ++t) {
        const int cur = t & 1;
        const int kcn = ((t + 1) & 31) * 64;
        SA2(cur ^ 1, kcn);                 // 2 gloads for next tile
        VMW(2); BAR(); SCB();              // cur fully staged (all waves)
        RDA(a0, cur, 0); RDB(b0, cur, 0);
        RDA(a1, cur, 1); RDB(b1, cur, 1);  // 16 ds_reads
        SB4(cur ^ 1, kcn);                 // 4 gloads for next tile
        MMX(a0, b0);                       // compiler inserts lgkm waits
        MMX(a1, b1);
        SCB(); BAR();                      // all waves done reading cur
    }

    // epilogue
    #pragma unroll
    for (int f = 0; f < 4; ++f)
        #pragma unroll
        for (int n = 0; n < 4; ++n) {
            int row = bm0 + wr * 64 + f * 16 + lq * 4;
            int col = bn0 + wc * 64 + n * 16 + l16;
            if (OUTF32) {
                float* C = (float*)Cv;
                #pragma unroll
                for (int r = 0; r < 4; ++r)
                    C[(size_t)(row + r) * N + col] = acc[f][n][r];
            } else {
                ushort* C = (ushort*)Cv;
                #pragma unroll
                for (int r = 0; r < 4; ++r)
                    C[(size_t)(row + r) * N + col] = f2bf(acc[f][n][r]);
            }
        }
}

// ---------------- Flash attention (v3: log2 softmax, defer-max, cvt_pk) --
__global__ __launch_bounds__(256, 2) void attn_k(const ushort* __restrict__ qkv,
                                                 const ushort* __restrict__ vt,
                                                 ushort* __restrict__ aout) {
    extern __shared__ char asmem[];

    const int bid = blockIdx.x;
    const int L = (bid & 7) * 64 + (bid >> 3);
    const int qt = L & 15, bh = L >> 4;
    const int b = bh >> 4, h = bh & 15;
    const int tid = threadIdx.x;
    const int w = tid >> 6, lane = tid & 63;
    const int l16 = lane & 15, lq = lane >> 4;

    s16x8 qf[2][4];
    #pragma unroll
    for (int qb = 0; qb < 2; ++qb) {
        size_t qbase = (size_t)(b * SS + qt * 128 + w * 32 + qb * 16 + l16) * QKVN + h * HDD;
        #pragma unroll
        for (int kk = 0; kk < 4; ++kk)
            qf[qb][kk] = *(const s16x8*)(qkv + qbase + kk * 32 + lq * 8);
    }

    const ushort* ksrc[4];
    const ushort* vsrc[4];
    #pragma unroll
    for (int i = 0; i < 4; ++i) {
        int krow = w * 16 + i * 4 + (lane >> 4);
        int kcolb = ((lane & 15) * 16) ^ ((krow & 7) << 4);
        ksrc[i] = qkv + (size_t)(b * SS + krow) * QKVN + HIDD + h * HDD + kcolb / 2;
        int drow = w * 32 + i * 8 + (lane >> 3);
        int vcolb = ((lane & 7) * 16) ^ ((drow & 7) << 4);
        vsrc[i] = vt + ((size_t)(b * NHH + h) * HDD + drow) * SS + vcolb / 2;
    }

    f32x4 accO[2][8] = {};
    float mrow[2] = {-3e38f, -3e38f};
    float lrow[2] = {0.f, 0.f};

    char* Pb = asmem + 65536 + w * 4096;
    const int kswz = (l16 & 7) << 4;
    const int pswz = (l16 & 3) << 5;

    {
        char* kb = asmem + w * 4096;
        char* vb = asmem + 32768 + w * 4096;
        #pragma unroll
        for (int i = 0; i < 4; ++i) {
            GL_LDS(ksrc[i], kb + i * 1024); ksrc[i] += 64 * QKVN;
            GL_LDS(vsrc[i], vb + i * 1024); vsrc[i] += 64;
        }
    }
    __syncthreads();

    for (int t = 0; t < 32; ++t) {
        const int cur = t & 1;
        if (t < 31) {
            char* kb = asmem + (cur ^ 1) * 16384 + w * 4096;
            char* vb = asmem + 32768 + (cur ^ 1) * 16384 + w * 4096;
            #pragma unroll
            for (int i = 0; i < 4; ++i) {
                GL_LDS(ksrc[i], kb + i * 1024); ksrc[i] += 64 * QKVN;
                GL_LDS(vsrc[i], vb + i * 1024); vsrc[i] += 64;
            }
        }
        const char* Kb = asmem + cur * 16384;
        const char* Vb = asmem + 32768 + cur * 16384;

        // S^T = K . Q  (scores already in log2 domain via Q pre-scale)
        f32x4 sc[2][4] = {};
        #pragma unroll
        for (int nb = 0; nb < 4; ++nb) {
            int rbase = (nb * 16 + l16) * 256;
            #pragma unroll
            for (int kk = 0; kk < 4; ++kk) {
                s16x8 kf = *(const s16x8*)(Kb + rbase + ((kk * 64 + lq * 16) ^ kswz));
                sc[0][nb] = __builtin_amdgcn_mfma_f32_16x16x32_bf16(kf, qf[0][kk], sc[0][nb], 0, 0, 0);
                sc[1][nb] = __builtin_amdgcn_mfma_f32_16x16x32_bf16(kf, qf[1][kk], sc[1][nb], 0, 0, 0);
            }
        }

        // online softmax with defer-max (T13): row = q = qb*16+l16
        float pmax[2];
        #pragma unroll
        for (int qb = 0; qb < 2; ++qb) {
            float m0 = fmaxf(fmaxf(fmaxf(sc[qb][0][0], sc[qb][0][1]), fmaxf(sc[qb][0][2], sc[qb][0][3])),
                             fmaxf(fmaxf(sc[qb][1][0], sc[qb][1][1]), fmaxf(sc[qb][1][2], sc[qb][1][3])));
            m0 = fmaxf(m0, fmaxf(fmaxf(fmaxf(sc[qb][2][0], sc[qb][2][1]), fmaxf(sc[qb][2][2], sc[qb][2][3])),
                                 fmaxf(fmaxf(sc[qb][3][0], sc[qb][3][1]), fmaxf(sc[qb][3][2], sc[qb][3][3]))));
            m0 = fmaxf(m0, __shfl_xor(m0, 16));
            m0 = fmaxf(m0, __shfl_xor(m0, 32));
            pmax[qb] = m0;
        }
        #pragma unroll
        for (int qb = 0; qb < 2; ++qb) {
            if (__all(pmax[qb] - mrow[qb] <= 8.0f)) {
                float mm = mrow[qb];
                float s = 0.f;
                #pragma unroll
                for (int nb = 0; nb < 4; ++nb)
                    #pragma unroll
                    for (int r = 0; r < 4; ++r) {
                        float pv = EXP2(sc[qb][nb][r] - mm);
                        sc[qb][nb][r] = pv;
                        s += pv;
                    }
                s += __shfl_xor(s, 16);
                s += __shfl_xor(s, 32);
                lrow[qb] += s;
            } else {
                float mnew = fmaxf(mrow[qb], pmax[qb]);
                float sclv = EXP2(mrow[qb] - mnew);
                mrow[qb] = mnew;
                float s = 0.f;
                #pragma unroll
                for (int nb = 0; nb < 4; ++nb)
                    #pragma unroll
                    for (int r = 0; r < 4; ++r) {
                        float pv = EXP2(sc[qb][nb][r] - mnew);
                        sc[qb][nb][r] = pv;
                        s += pv;
                    }
                s += __shfl_xor(s, 16);
                s += __shfl_xor(s, 32);
                lrow[qb] = lrow[qb] * sclv + s;
                #pragma unroll
                for (int r = 0; r < 4; ++r) {
                    float sr = __shfl(sclv, lq * 4 + r);
                    #pragma unroll
                    for (int ob = 0; ob < 8; ++ob)
                        accO[qb][ob][r] *= sr;
                }
            }
        }

        // P -> per-wave swizzled LDS via v_cvt_pk_bf16_f32
        #pragma unroll
        for (int qb = 0; qb < 2; ++qb) {
            int qrow = (qb * 16 + l16) * 128;
            #pragma unroll
            for (int nb = 0; nb < 4; ++nb) {
                uint2 v2 = make_uint2(cvtpk(sc[qb][nb][0], sc[qb][nb][1]),
                                      cvtpk(sc[qb][nb][2], sc[qb][nb][3]));
                *(uint2*)(Pb + qrow + ((nb * 32 + lq * 8) ^ pswz)) = v2;
            }
        }

        // O += P . V
        #pragma unroll
        for (int kk2 = 0; kk2 < 2; ++kk2) {
            int cb = (kk2 * 64 + lq * 16);
            s16x8 pf0 = *(const s16x8*)(Pb + l16 * 128 + (cb ^ pswz));
            s16x8 pf1 = *(const s16x8*)(Pb + (16 + l16) * 128 + (cb ^ pswz));
            #pragma unroll
            for (int ob = 0; ob < 8; ++ob) {
                int d = ob * 16 + l16;
                s16x8 vf = *(const s16x8*)(Vb + d * 128 + (cb ^ ((d & 7) << 4)));
                accO[0][ob] = __builtin_amdgcn_mfma_f32_16x16x32_bf16(pf0, vf, accO[0][ob], 0, 0, 0);
                accO[1][ob] = __builtin_amdgcn_mfma_f32_16x16x32_bf16(pf1, vf, accO[1][ob], 0, 0, 0);
            }
        }
        __syncthreads();
    }

    float inv0 = 1.f / lrow[0], inv1 = 1.f / lrow[1];
    #pragma unroll
    for (int r = 0; r < 4; ++r) {
        float i0 = __shfl(inv0, lq * 4 + r);
        float i1 = __shfl(inv1, lq * 4 + r);
        int row0 = b * SS + qt * 128 + w * 32 + lq * 4 + r;
        #pragma unroll
        for (int ob = 0; ob < 8; ++ob) {
            int col = h * HDD + ob * 16 + l16;
            aout[(size_t)row0 * HIDD + col] = f2bf(accO[0][ob][r] * i0);
            aout[(size_t)(row0 + 16) * HIDD + col] = f2bf(accO[1][ob][r] * i1);
        }
    }
}

// ---------------- launch -------------------------------------------------
extern "C" void kernel_launch(void* const* d_in, const int* in_sizes, int n_in,
                              void* d_out, int out_size, void* d_ws, size_t ws_size,
                              hipStream_t stream) {
    const float* x     = (const float*)d_in[0];
    const float* w_qkv = (const float*)d_in[1];
    const float* w_out = (const float*)d_in[2];
    float* out = (float*)d_out;

    char* ws = (char*)d_ws;
    ushort* qkv_bf  = (ushort*)(ws);
    ushort* xbf     = (ushort*)(ws + 50331648);
    ushort* wq_bf   = (ushort*)(ws + 67108864);
    ushort* vtbuf   = (ushort*)(ws + 67108864);
    ushort* wout_bf = (ushort*)(ws + 67108864 + 16777216);
    float2* tab     = (float2*)(ws + 92274688);

    cvt_f32_bf16<<<2048, 256, 0, stream>>>(x, xbf, (NROWS * HIDD) / 4);
    cvt_f32_bf16<<<2048, 256, 0, stream>>>(w_qkv, wq_bf, (QKVN * HIDD) / 4);
    rope_table_k<<<(SS * 64) / 256, 256, 0, stream>>>(tab);

    // QKV projection: 128x256 tiles -> 32*24 = 768 blocks (3/CU exact)
    gemm128<0><<<(NROWS / 128) * (QKVN / 256), 512, 0, stream>>>(xbf, wq_bf, qkv_bf, QKVN);

    rope_apply_k<<<(NROWS * 2 * NHH * 64) / 256, 256, 0, stream>>>(qkv_bf, tab,
                                                                   out + (size_t)NROWS * HIDD);
    vtrans_k<<<2048, 256, 0, stream>>>(qkv_bf, vtbuf);
    cvt_f32_bf16<<<2048, 256, 0, stream>>>(w_out, wout_bf, (HIDD * HIDD) / 4);

    attn_k<<<512, 256, 81920, stream>>>(qkv_bf, vtbuf, xbf);

    // output projection: 32*8 = 256 blocks (1/CU exact), fp32 out
    gemm128<1><<<(NROWS / 128) * (HIDD / 256), 512, 0, stream>>>(xbf, wout_bf, out, HIDD);
}